// Round 8
// baseline (3307.164 us; speedup 1.0000x reference)
//
#include <hip/hip_runtime.h>
#include <hip/hip_cooperative_groups.h>
#include <math.h>

namespace cg = cooperative_groups;

#define CDIM 256
#define LSEQ 4096
#define NBH 16
#define NPTS 65536
#define KC 256

__device__ __forceinline__ float fadd(float a, float b){ return __fadd_rn(a,b); }
__device__ __forceinline__ float fmul(float a, float b){ return __fmul_rn(a,b); }
__device__ __forceinline__ float fsub(float a, float b){ return __fsub_rn(a,b); }

// numpy contiguous n=32 float32 sum, AVX-512 npyv path (verified R5)
__device__ __forceinline__ float sum32_np(const float* e){
    float l[16];
    #pragma unroll
    for (int j = 0; j < 16; j++) l[j] = fadd(e[j], e[j + 16]);
    float t3[8];
    #pragma unroll
    for (int j = 0; j < 8; j++) t3[j] = fadd(l[j], l[j + 8]);
    float t6[4];
    #pragma unroll
    for (int j = 0; j < 4; j++) t6[j] = fadd(t3[j], t3[j + 4]);
    return fadd(fadd(t6[0], t6[2]), fadd(t6[1], t6[3]));
}

// ---------- LayerNorm, numpy semantics (sequential over c) ----------
__global__ __launch_bounds__(64) void ln_np(const float* __restrict__ x,
        const float* __restrict__ g, const float* __restrict__ bt,
        float* __restrict__ y) {
    int gid = blockIdx.x * 64 + threadIdx.x;
    int b = gid >> 12, l = gid & 4095;
    const float* xb = x + (size_t)b * CDIM * LSEQ + l;
    float s = 0.f;
    for (int c = 0; c < 256; c++) s = fadd(s, xb[(size_t)c * LSEQ]);
    float mean = __fdiv_rn(s, 256.f);
    float s2 = 0.f;
    for (int c = 0; c < 256; c++) {
        float d = fsub(xb[(size_t)c * LSEQ], mean);
        s2 = fadd(s2, fmul(d, d));
    }
    float var = __fdiv_rn(s2, 256.f);
    float den = fadd(__fsqrt_rn(var), 1e-6f);
    float* yb = y + (size_t)b * CDIM * LSEQ + l;
    for (int c = 0; c < 256; c++) {
        float d = fsub(xb[(size_t)c * LSEQ], mean);
        yb[(size_t)c * LSEQ] = fadd(__fdiv_rn(fmul(g[c], d), den), bt[c]);
    }
}

// ---------- conv1x1, numpy einsum SOP semantics ---------------------
template<int COT>
__global__ __launch_bounds__(256) void conv_t(const float* __restrict__ W, int wrow0,
        const float* __restrict__ X, float* __restrict__ Y, int nrows) {
    __shared__ float ws[COT * 256];
    int tid = threadIdx.x;
    int l = blockIdx.x * 256 + tid;
    int o0 = blockIdx.y * COT;
    int b = blockIdx.z;
    {
        const float4* wb4 = (const float4*)(W + (size_t)(wrow0 + o0) * CDIM);
        float4* ws4 = (float4*)ws;
        for (int i = tid; i < COT * 64; i += 256) ws4[i] = wb4[i];
    }
    __syncthreads();
    const float* xb = X + (size_t)b * CDIM * LSEQ + l;
    float acc[COT];
    #pragma unroll
    for (int i = 0; i < COT; i++) acc[i] = 0.f;
    const float4* ws4 = (const float4*)ws;
    for (int c = 0; c < 256; c += 4) {
        float x0 = xb[(size_t)(c + 0) * LSEQ];
        float x1 = xb[(size_t)(c + 1) * LSEQ];
        float x2 = xb[(size_t)(c + 2) * LSEQ];
        float x3 = xb[(size_t)(c + 3) * LSEQ];
        #pragma unroll
        for (int oo = 0; oo < COT; oo++) {
            float4 w = ws4[(oo * 256 + c) >> 2];
            acc[oo] = fadd(acc[oo], fmul(w.x, x0));
            acc[oo] = fadd(acc[oo], fmul(w.y, x1));
            acc[oo] = fadd(acc[oo], fmul(w.z, x2));
            acc[oo] = fadd(acc[oo], fmul(w.w, x3));
        }
    }
    for (int oo = 0; oo < COT; oo++)
        Y[((size_t)b * nrows + o0 + oo) * LSEQ + l] = acc[oo];
}

// ---------- fold (+ optional l2norm) --------------------------------
__global__ __launch_bounds__(256) void fold_np(const float* __restrict__ src,
        int srcRows, int row0, int donorm, float* __restrict__ dst) {
    int p = blockIdx.x * 256 + threadIdx.x;
    int bh = p >> 12, l = p & 4095;
    int b = bh >> 3, h = bh & 7;
    const float* sp = src + ((size_t)b * srcRows + row0 + h * 32) * LSEQ + l;
    float x[32];
    #pragma unroll
    for (int t = 0; t < 32; t++) x[t] = sp[(size_t)t * LSEQ];
    float4* dp4 = (float4*)(dst + (size_t)p * 32);
    if (donorm) {
        float ss = 0.f;
        #pragma unroll
        for (int t = 0; t < 32; t++) ss = fadd(ss, fmul(x[t], x[t]));
        float n = __fsqrt_rn(ss);
        float den = fmaxf(n, 1e-12f);
        #pragma unroll
        for (int t = 0; t < 32; t++) x[t] = __fdiv_rn(x[t], den);
    }
    #pragma unroll
    for (int t = 0; t < 8; t++)
        dp4[t] = make_float4(x[4*t], x[4*t+1], x[4*t+2], x[4*t+3]);
}

// ---------- ||x||^2 per point (AVX-512 tree) ------------------------
__global__ __launch_bounds__(256) void xx_np(const float* __restrict__ pts,
        float* __restrict__ xx) {
    int p = blockIdx.x * 256 + threadIdx.x;
    const float4* x4 = (const float4*)(pts + (size_t)p * 32);
    float x[32];
    #pragma unroll
    for (int t = 0; t < 8; t++) {
        float4 f = x4[t];
        x[4*t] = f.x; x[4*t+1] = f.y; x[4*t+2] = f.z; x[4*t+3] = f.w;
    }
    float e[32];
    #pragma unroll
    for (int t = 0; t < 32; t++) e[t] = fmul(x[t], x[t]);
    xx[p] = sum32_np(e);
}

// ==================================================================
// Fused k-means: prologue (xx, cent/cc init) + 10 x {assign+hist,
// chunk-scan, cbase+scatter, ordered-sum+update+cc}. Cooperative.
// grid 512 x 256. All fp32 ops/orders identical to R7 kernels.
// ==================================================================
#define STILE 128
__global__ __launch_bounds__(256) void kmeans_fused(
        const float* __restrict__ pts, float* __restrict__ xx,
        float* __restrict__ cent, float* __restrict__ cc,
        int* __restrict__ asn, int* __restrict__ hist,
        int* __restrict__ chunkbase, int* __restrict__ totals,
        int* __restrict__ perm) {
    cg::grid_group grid = cg::this_grid();
    __shared__ union {
        struct { float sc[8192]; float scc[256]; int bins[256]; } a;   // assign
        struct { int loc[257]; } b;                                    // chunk scan
        struct { int cb[256]; int asn_l[128]; } c;                     // scatter
        struct { float buf[2][STILE][32]; } d;                         // sumk
    } sm;
    int tid = threadIdx.x, blk = blockIdx.x;

    // ---- prologue: xx for all points; cent/cc init for clusters ----
    if (tid < 128) {
        int p = blk * 128 + tid;
        const float4* x4 = (const float4*)(pts + (size_t)p * 32);
        float x[32];
        #pragma unroll
        for (int t = 0; t < 8; t++) {
            float4 f = x4[t];
            x[4*t] = f.x; x[4*t+1] = f.y; x[4*t+2] = f.z; x[4*t+3] = f.w;
        }
        float e[32];
        #pragma unroll
        for (int t = 0; t < 32; t++) e[t] = fmul(x[t], x[t]);
        xx[p] = sum32_np(e);
    }
    if (blk < 256 && tid < 32) {
        float v = pts[(size_t)blk * 32 + tid];
        cent[(size_t)blk * 32 + tid] = v;
        float e = fmul(v, v);
        e = fadd(e, __shfl_xor(e, 16));
        e = fadd(e, __shfl_xor(e, 8));
        e = fadd(e, __shfl_xor(e, 4));
        e = fadd(e, __shfl_xor(e, 2));
        e = fadd(e, __shfl_xor(e, 1));
        if (tid == 0) cc[blk] = e;
    }
    grid.sync();

    int tot_j = 0;
    for (int it = 0; it < 10; it++) {
        // ---- phase A: assign (2 threads/point, half-split argmin) --
        {
            const float4* c4 = (const float4*)cent;
            float4* s4 = (float4*)sm.a.sc;
            for (int i = tid; i < 2048; i += 256) s4[i] = c4[i];
            sm.a.scc[tid] = cc[tid];
            sm.a.bins[tid] = 0;
            __syncthreads();
            int pl = tid >> 1;              // 0..127
            int half = tid & 1;             // cluster half
            int p = blk * 128 + pl;
            float x[32];
            {
                const float4* pp = (const float4*)(pts + (size_t)p * 32);
                #pragma unroll
                for (int t = 0; t < 8; t++) {
                    float4 f = pp[t];
                    x[4*t] = f.x; x[4*t+1] = f.y; x[4*t+2] = f.z; x[4*t+3] = f.w;
                }
            }
            float xp = xx[p];
            float bd = 3.4e38f; int bj = 0;
            int jbase = half * 128;
            for (int jj = 0; jj < 128; jj++) {
                int j = jbase + jj;
                const float4* cj = (const float4*)(sm.a.sc + j * 32);
                float g = 0.f;
                #pragma unroll
                for (int t = 0; t < 8; t++) {
                    float4 w = cj[t];
                    g = __builtin_fmaf(x[4*t],   w.x, g);
                    g = __builtin_fmaf(x[4*t+1], w.y, g);
                    g = __builtin_fmaf(x[4*t+2], w.z, g);
                    g = __builtin_fmaf(x[4*t+3], w.w, g);
                }
                float d = fadd(fsub(xp, fmul(2.f, g)), sm.a.scc[j]);
                if (d < bd) { bd = d; bj = j; }
            }
            // merge halves: comparison-only -> identical to sequential 0..255
            float bd1 = __shfl_xor(bd, 1);
            int   bj1 = __shfl_xor(bj, 1);
            if (half == 0) {
                if (bd1 < bd) { bd = bd1; bj = bj1; }
                asn[p] = bj;
                atomicAdd(&sm.a.bins[bj], 1);
            }
            __syncthreads();
            hist[blk * 256 + tid] = sm.a.bins[tid];
        }
        grid.sync();
        // ---- phase B: per-cluster prefix over 512 chunks -----------
        if (blk < 256) {
            int j = blk;
            int c0 = tid * 2;
            int h0 = hist[(size_t)c0 * 256 + j];
            int h1 = hist[(size_t)(c0 + 1) * 256 + j];
            sm.b.loc[tid] = h0 + h1;
            __syncthreads();
            if (tid == 0) {
                int run = 0;
                for (int u = 0; u < 256; u++) {
                    int v = sm.b.loc[u]; sm.b.loc[u] = run; run += v;
                }
                sm.b.loc[256] = run;
            }
            __syncthreads();
            int base = sm.b.loc[tid];
            chunkbase[(size_t)c0 * 256 + j] = base;
            chunkbase[(size_t)(c0 + 1) * 256 + j] = base + h0;
            tot_j = sm.b.loc[256];
            if (tid == 0) totals[j] = tot_j;
        }
        grid.sync();
        // ---- phase C: redundant cbase scan + stable scatter --------
        int cbase_j;
        {
            sm.c.cb[tid] = totals[tid];
            __syncthreads();
            if (tid == 0) {
                int run = 0;
                for (int u = 0; u < 256; u++) {
                    int v = sm.c.cb[u]; sm.c.cb[u] = run; run += v;
                }
            }
            __syncthreads();
            cbase_j = (blk < 256) ? sm.c.cb[blk] : 0;
            if (tid < 128) sm.c.asn_l[tid] = asn[blk * 128 + tid];
            __syncthreads();
            if (tid < 128) {
                int my = sm.c.asn_l[tid];
                int r = 0;
                for (int i = 0; i < tid; i++) r += (sm.c.asn_l[i] == my) ? 1 : 0;
                perm[sm.c.cb[my] + chunkbase[(size_t)blk * 256 + my] + r] = blk * 128 + tid;
            }
            __syncthreads();
        }
        grid.sync();
        // ---- phase D: ordered sum + update + cc --------------------
        if (blk < 256) {
            int j = blk, base = cbase_j, n = tot_j;
            int t = tid & 31, r0 = tid >> 5;
            for (int r = r0; r < STILE; r += 8) {
                if (r < n) sm.d.buf[0][r][t] = pts[(size_t)perm[base + r] * 32 + t];
            }
            __syncthreads();
            float s = 0.f;
            int b = 0;
            for (int i0 = 0; i0 < n; i0 += STILE, b ^= 1) {
                int nx = i0 + STILE;
                if (nx < n) {
                    for (int r = r0; r < STILE; r += 8) {
                        int gg = nx + r;
                        if (gg < n) sm.d.buf[b ^ 1][r][t] = pts[(size_t)perm[base + gg] * 32 + t];
                    }
                }
                if (tid < 32) {
                    int m = n - i0; if (m > STILE) m = STILE;
                    int i = 0;
                    for (; i + 4 <= m; i += 4) {
                        s = fadd(s, sm.d.buf[b][i][tid]);
                        s = fadd(s, sm.d.buf[b][i + 1][tid]);
                        s = fadd(s, sm.d.buf[b][i + 2][tid]);
                        s = fadd(s, sm.d.buf[b][i + 3][tid]);
                    }
                    for (; i < m; i++) s = fadd(s, sm.d.buf[b][i][tid]);
                }
                __syncthreads();
            }
            if (tid < 32) {
                float v;
                if (n > 0) {
                    v = __fdiv_rn(s, (float)n);
                    cent[(size_t)j * 32 + tid] = v;
                } else {
                    v = cent[(size_t)j * 32 + tid];
                }
                float e = fmul(v, v);
                e = fadd(e, __shfl_xor(e, 16));
                e = fadd(e, __shfl_xor(e, 8));
                e = fadd(e, __shfl_xor(e, 4));
                e = fadd(e, __shfl_xor(e, 2));
                e = fadd(e, __shfl_xor(e, 1));
                if (tid == 0) cc[j] = e;
            }
        }
        grid.sync();
    }
}

// ---------- key assign + L1 dist (LDS-staged) -----------------------
__global__ __launch_bounds__(256) void kdist_np(const float* __restrict__ pts,
        const float* __restrict__ xx, const float* __restrict__ cent,
        const float* __restrict__ cc, float* __restrict__ kd) {
    __shared__ float sc[8192];
    __shared__ float scc[256];
    int tid = threadIdx.x;
    {
        const float4* c4 = (const float4*)cent;
        float4* s4 = (float4*)sc;
        for (int i = tid; i < 2048; i += 256) s4[i] = c4[i];
    }
    scc[tid] = cc[tid];
    __syncthreads();
    int p = blockIdx.x * 256 + tid;
    float x[32];
    {
        const float4* pp = (const float4*)(pts + (size_t)p * 32);
        #pragma unroll
        for (int t = 0; t < 8; t++) {
            float4 f = pp[t];
            x[4*t] = f.x; x[4*t+1] = f.y; x[4*t+2] = f.z; x[4*t+3] = f.w;
        }
    }
    float xp = xx[p];
    float bd = 3.4e38f; int bj = 0;
    #pragma unroll 2
    for (int j = 0; j < 256; j++) {
        const float4* cj = (const float4*)(sc + j * 32);
        float g = 0.f;
        #pragma unroll
        for (int t = 0; t < 8; t++) {
            float4 w = cj[t];
            g = __builtin_fmaf(x[4*t],   w.x, g);
            g = __builtin_fmaf(x[4*t+1], w.y, g);
            g = __builtin_fmaf(x[4*t+2], w.z, g);
            g = __builtin_fmaf(x[4*t+3], w.w, g);
        }
        float d = fadd(fsub(xp, fmul(2.f, g)), scc[j]);
        if (d < bd) { bd = d; bj = j; }
    }
    const float* cb = &sc[bj * 32];
    float e[32];
    #pragma unroll
    for (int t = 0; t < 32; t++) e[t] = fabsf(fsub(cb[t], x[t]));
    kd[p] = sum32_np(e);
}

// ---------- top-256 via radix select (exact stable set) + gather ----
__global__ __launch_bounds__(256) void topk_v2(const float* __restrict__ kd,
        const float* __restrict__ k_t, const float* __restrict__ v_t,
        float* __restrict__ ksel, float* __restrict__ vsel) {
    __shared__ unsigned uv[4096];
    __shared__ int hist[256];
    __shared__ unsigned s_prefix;
    __shared__ int s_rem;
    __shared__ int sc1[256];
    __shared__ int out_src[256];
    int bh = blockIdx.x, tid = threadIdx.x;
    for (int i = tid; i < 4096; i += 256) uv[i] = __float_as_uint(kd[bh * 4096 + i]);
    if (tid == 0) { s_prefix = 0u; s_rem = 256; }
    out_src[tid] = 0;
    __syncthreads();
    for (int pass = 0; pass < 4; pass++) {
        int shift = 24 - 8 * pass;
        hist[tid] = 0;
        __syncthreads();
        unsigned pfx = s_prefix;
        for (int i = tid; i < 4096; i += 256) {
            unsigned u = uv[i];
            bool in = (pass == 0) || ((u >> (shift + 8)) == (pfx >> (shift + 8)));
            if (in) atomicAdd(&hist[(u >> shift) & 255], 1);
        }
        __syncthreads();
        if (tid == 0) {
            int rem = s_rem, cum = 0, b;
            for (b = 255; b >= 0; b--) {
                if (cum + hist[b] >= rem) break;
                cum += hist[b];
            }
            s_rem = rem - cum;
            s_prefix = s_prefix | ((unsigned)b << shift);
        }
        __syncthreads();
    }
    unsigned T = s_prefix;
    int r = s_rem;
    int base_i = tid * 16;
    int ec = 0;
    for (int q = 0; q < 16; q++) ec += (uv[base_i + q] == T) ? 1 : 0;
    sc1[tid] = ec;
    __syncthreads();
    for (int d = 1; d < 256; d <<= 1) {
        int t0 = sc1[tid];
        int u0 = (tid >= d) ? sc1[tid - d] : 0;
        __syncthreads();
        sc1[tid] = t0 + u0;
        __syncthreads();
    }
    int erank = (tid == 0) ? 0 : sc1[tid - 1];
    __syncthreads();
    bool incl[16];
    int ic = 0;
    for (int q = 0; q < 16; q++) {
        unsigned u = uv[base_i + q];
        bool inc;
        if (u > T) inc = true;
        else if (u == T) { inc = (erank < r); erank++; }
        else inc = false;
        incl[q] = inc;
        ic += inc ? 1 : 0;
    }
    sc1[tid] = ic;
    __syncthreads();
    for (int d = 1; d < 256; d <<= 1) {
        int t0 = sc1[tid];
        int u0 = (tid >= d) ? sc1[tid - d] : 0;
        __syncthreads();
        sc1[tid] = t0 + u0;
        __syncthreads();
    }
    int pos = (tid == 0) ? 0 : sc1[tid - 1];
    for (int q = 0; q < 16; q++) {
        if (incl[q]) out_src[pos++] = base_i + q;
    }
    __syncthreads();
    for (int e = tid; e < 256 * 32; e += 256) {
        int jj = e >> 5, t = e & 31;
        int src = out_src[jj];
        ksel[(size_t)bh * 8192 + e] = k_t[((size_t)bh * 4096 + src) * 32 + t];
        vsel[(size_t)bh * 8192 + e] = v_t[((size_t)bh * 4096 + src) * 32 + t];
    }
}

// ---------- attention v2: fixed-shift softmax (s<=1), lane-pair split
__global__ __launch_bounds__(256) void attn_v2(const float* __restrict__ q_t,
        const float* __restrict__ ksel, const float* __restrict__ vsel,
        float* __restrict__ out) {
    __shared__ float sk[8192];
    __shared__ float sv[8192];
    int bh = blockIdx.y, tid = threadIdx.x;
    {
        const float4* gk = (const float4*)(ksel + (size_t)bh * 8192);
        const float4* gv = (const float4*)(vsel + (size_t)bh * 8192);
        float4* k4s = (float4*)sk; float4* v4s = (float4*)sv;
        for (int i = tid; i < 2048; i += 256) { k4s[i] = gk[i]; v4s[i] = gv[i]; }
    }
    __syncthreads();
    int ql = tid >> 1, slice = tid & 1;
    int p = bh * 4096 + blockIdx.x * 128 + ql;
    float q[32];
    {
        const float4* qp = (const float4*)(q_t + (size_t)p * 32);
        #pragma unroll
        for (int t = 0; t < 8; t++) {
            float4 f = qp[t];
            q[4*t] = f.x; q[4*t+1] = f.y; q[4*t+2] = f.z; q[4*t+3] = f.w;
        }
    }
    float o[32];
    #pragma unroll
    for (int t = 0; t < 32; t++) o[t] = 0.f;
    float lsum = 0.f;
    const float4* k4 = (const float4*)sk;
    const float4* v4 = (const float4*)sv;
    int j0 = slice * 128;
    for (int j = j0; j < j0 + 128; j++) {
        float s = 0.f;
        #pragma unroll
        for (int t = 0; t < 8; t++) {
            float4 kf = k4[j * 8 + t];
            s += q[4*t]*kf.x + q[4*t+1]*kf.y + q[4*t+2]*kf.z + q[4*t+3]*kf.w;
        }
        float w = __expf(s - 1.0f);   // s <= 1 (unit vectors): no overflow
        lsum += w;
        #pragma unroll
        for (int t = 0; t < 8; t++) {
            float4 vf = v4[j * 8 + t];
            o[4*t]   += w * vf.x;
            o[4*t+1] += w * vf.y;
            o[4*t+2] += w * vf.z;
            o[4*t+3] += w * vf.w;
        }
    }
    // merge lane pairs
    #pragma unroll
    for (int t = 0; t < 32; t++) o[t] += __shfl_xor(o[t], 1);
    lsum += __shfl_xor(lsum, 1);
    if (slice == 0) {
        float inv = 1.f / lsum;
        float4* op = (float4*)(out + (size_t)p * 32);
        #pragma unroll
        for (int t = 0; t < 8; t++)
            op[t] = make_float4(o[4*t]*inv, o[4*t+1]*inv, o[4*t+2]*inv, o[4*t+3]*inv);
    }
}

// ---------- unfold (bh,L,32) -> (b,256,L) ---------------------------
__global__ __launch_bounds__(256) void unfold_kernel(const float* __restrict__ att,
        float* __restrict__ Fo) {
    __shared__ float tbuf[32][65];
    int bh = blockIdx.y, l0 = blockIdx.x * 64;
    int b = bh >> 3, h = bh & 7;
    int tid = threadIdx.x;
    #pragma unroll
    for (int r = 0; r < 8; r++) {
        int e = r * 256 + tid;
        int l = e >> 5, d = e & 31;
        tbuf[d][l] = att[((size_t)bh * 4096 + l0 + l) * 32 + d];
    }
    __syncthreads();
    #pragma unroll
    for (int r = 0; r < 8; r++) {
        int e = r * 256 + tid;
        int d = e >> 6, l = e & 63;
        Fo[((size_t)b * 256 + h * 32 + d) * LSEQ + l0 + l] = tbuf[d][l];
    }
}

// ---------- final LN + scale + residual (numpy orders) --------------
__global__ __launch_bounds__(64) void lnres_np(const float* __restrict__ x,
        const float* __restrict__ g, const float* __restrict__ bt,
        const float* __restrict__ gs, const float* __restrict__ qsrc,
        float* __restrict__ y) {
    int gid = blockIdx.x * 64 + threadIdx.x;
    int b = gid >> 12, l = gid & 4095;
    const float* xb = x + (size_t)b * CDIM * LSEQ + l;
    float s = 0.f;
    for (int c = 0; c < 256; c++) s = fadd(s, xb[(size_t)c * LSEQ]);
    float mean = __fdiv_rn(s, 256.f);
    float s2 = 0.f;
    for (int c = 0; c < 256; c++) {
        float d = fsub(xb[(size_t)c * LSEQ], mean);
        s2 = fadd(s2, fmul(d, d));
    }
    float var = __fdiv_rn(s2, 256.f);
    float den = fadd(__fsqrt_rn(var), 1e-6f);
    float scale = gs[0];
    const float* qb = qsrc + (size_t)b * CDIM * LSEQ + l;
    float* yb = y + (size_t)b * CDIM * LSEQ + l;
    for (int c = 0; c < 256; c++) {
        float d = fsub(xb[(size_t)c * LSEQ], mean);
        float r = fadd(__fdiv_rn(fmul(g[c], d), den), bt[c]);
        yb[(size_t)c * LSEQ] = fadd(fmul(scale, r), qb[(size_t)c * LSEQ]);
    }
}

// ==================================================================
extern "C" void kernel_launch(void* const* d_in, const int* in_sizes, int n_in,
                              void* d_out, int out_size, void* d_ws, size_t ws_size,
                              hipStream_t stream) {
    const float* qsrc   = (const float*)d_in[0];
    const float* ctx    = (const float*)d_in[1];
    const float* w_q    = (const float*)d_in[2];
    const float* w_kv   = (const float*)d_in[3];
    const float* w_out  = (const float*)d_in[4];
    const float* g_ctx  = (const float*)d_in[5];
    const float* b_ctx  = (const float*)d_in[6];
    const float* g_q    = (const float*)d_in[7];
    const float* b_q    = (const float*)d_in[8];
    const float* g_out  = (const float*)d_in[9];
    const float* b_out  = (const float*)d_in[10];
    const float* gs     = (const float*)d_in[11];

    char* base = (char*)d_ws;
    const size_t MB = 1024 * 1024;
    float* yln   = (float*)base;               // [0,8) LN out; later att
    float* att   = (float*)base;
    float* kvbuf = (float*)(base + 8 * MB);    // [8,24) kv conv; later y32 [8,16)
    float* y32   = (float*)(base + 8 * MB);
    float* qbuf  = (float*)(base + 24 * MB);   // [24,32) q conv; later Fo
    float* Fo    = (float*)(base + 24 * MB);
    float* q_t   = (float*)(base + 32 * MB);   // [32,40)
    float* k_t   = (float*)(base + 40 * MB);   // [40,48)
    float* v_t   = (float*)(base + 48 * MB);   // [48,56)
    char* SM = base + 56 * MB;
    float* xx_q      = (float*)(SM + 0);            // 256 KB
    float* xx_k      = (float*)(SM + 256 * 1024);   // 256 KB
    float* cent      = (float*)(SM + 512 * 1024);   // 32 KB
    float* cc        = (float*)(SM + 576 * 1024);   // 1 KB
    int*   asn       = (int*)  (SM + 640 * 1024);   // 256 KB
    int*   totals    = (int*)  (SM + 896 * 1024);   // 1 KB
    int*   hist      = (int*)  (SM + 960 * 1024);   // 512 KB
    int*   chunkbase = (int*)  (SM + 1472 * 1024);  // 512 KB
    int*   perm      = (int*)  (SM + 1984 * 1024);  // 256 KB
    float* kd        = (float*)(SM + 2240 * 1024);  // 256 KB
    float* ksel      = (float*)(SM + 2496 * 1024);  // 512 KB
    float* vsel      = (float*)(SM + 3008 * 1024);  // 512 KB

    // context branch
    ln_np<<<128, 64, 0, stream>>>(ctx, g_ctx, b_ctx, yln);
    conv_t<32><<<dim3(16, 16, 2), 256, 0, stream>>>(w_kv, 0, yln, kvbuf, 512);
    fold_np<<<256, 256, 0, stream>>>(kvbuf, 512, 0, 1, k_t);
    fold_np<<<256, 256, 0, stream>>>(kvbuf, 512, 256, 0, v_t);
    // query branch
    ln_np<<<128, 64, 0, stream>>>(qsrc, g_q, b_q, yln);
    conv_t<16><<<dim3(16, 16, 2), 256, 0, stream>>>(w_q, 0, yln, qbuf, 256);
    fold_np<<<256, 256, 0, stream>>>(qbuf, 256, 0, 1, q_t);

    // fused k-means (cooperative: grid-wide barriers)
    {
        const float* pts = q_t;
        void* kargs[] = { (void*)&pts, (void*)&xx_q, (void*)&cent, (void*)&cc,
                          (void*)&asn, (void*)&hist, (void*)&chunkbase,
                          (void*)&totals, (void*)&perm };
        hipLaunchCooperativeKernel((const void*)kmeans_fused, dim3(512), dim3(256),
                                   kargs, 0, stream);
    }

    xx_np<<<256, 256, 0, stream>>>(k_t, xx_k);
    kdist_np<<<256, 256, 0, stream>>>(k_t, xx_k, cent, cc, kd);
    topk_v2<<<16, 256, 0, stream>>>(kd, k_t, v_t, ksel, vsel);
    attn_v2<<<dim3(32, 16), 256, 0, stream>>>(q_t, ksel, vsel, att);
    unfold_kernel<<<dim3(64, 16), 256, 0, stream>>>(att, Fo);
    conv_t<16><<<dim3(16, 16, 2), 256, 0, stream>>>(w_out, 0, Fo, y32, 256);
    lnres_np<<<128, 64, 0, stream>>>(y32, g_out, b_out, gs, qsrc, (float*)d_out);
}

// Round 9
// 1371.521 us; speedup vs baseline: 2.4113x; 2.4113x over previous
//
#include <hip/hip_runtime.h>
#include <math.h>

#define CDIM 256
#define LSEQ 4096
#define NBH 16
#define NPTS 65536
#define KC 256

__device__ __forceinline__ float fadd(float a, float b){ return __fadd_rn(a,b); }
__device__ __forceinline__ float fmul(float a, float b){ return __fmul_rn(a,b); }
__device__ __forceinline__ float fsub(float a, float b){ return __fsub_rn(a,b); }

// numpy contiguous n=32 float32 sum, AVX-512 npyv path (verified R5)
__device__ __forceinline__ float sum32_np(const float* e){
    float l[16];
    #pragma unroll
    for (int j = 0; j < 16; j++) l[j] = fadd(e[j], e[j + 16]);
    float t3[8];
    #pragma unroll
    for (int j = 0; j < 8; j++) t3[j] = fadd(l[j], l[j + 8]);
    float t6[4];
    #pragma unroll
    for (int j = 0; j < 4; j++) t6[j] = fadd(t3[j], t3[j + 4]);
    return fadd(fadd(t6[0], t6[2]), fadd(t6[1], t6[3]));
}

// ---------- LayerNorm, numpy semantics (sequential over c) ----------
__global__ __launch_bounds__(64) void ln_np(const float* __restrict__ x,
        const float* __restrict__ g, const float* __restrict__ bt,
        float* __restrict__ y) {
    int gid = blockIdx.x * 64 + threadIdx.x;
    int b = gid >> 12, l = gid & 4095;
    const float* xb = x + (size_t)b * CDIM * LSEQ + l;
    float s = 0.f;
    for (int c = 0; c < 256; c++) s = fadd(s, xb[(size_t)c * LSEQ]);
    float mean = __fdiv_rn(s, 256.f);
    float s2 = 0.f;
    for (int c = 0; c < 256; c++) {
        float d = fsub(xb[(size_t)c * LSEQ], mean);
        s2 = fadd(s2, fmul(d, d));
    }
    float var = __fdiv_rn(s2, 256.f);
    float den = fadd(__fsqrt_rn(var), 1e-6f);
    float* yb = y + (size_t)b * CDIM * LSEQ + l;
    for (int c = 0; c < 256; c++) {
        float d = fsub(xb[(size_t)c * LSEQ], mean);
        yb[(size_t)c * LSEQ] = fadd(__fdiv_rn(fmul(g[c], d), den), bt[c]);
    }
}

// ---------- conv1x1, numpy einsum SOP semantics ---------------------
template<int COT>
__global__ __launch_bounds__(256) void conv_t(const float* __restrict__ W, int wrow0,
        const float* __restrict__ X, float* __restrict__ Y, int nrows) {
    __shared__ float ws[COT * 256];
    int tid = threadIdx.x;
    int l = blockIdx.x * 256 + tid;
    int o0 = blockIdx.y * COT;
    int b = blockIdx.z;
    {
        const float4* wb4 = (const float4*)(W + (size_t)(wrow0 + o0) * CDIM);
        float4* ws4 = (float4*)ws;
        for (int i = tid; i < COT * 64; i += 256) ws4[i] = wb4[i];
    }
    __syncthreads();
    const float* xb = X + (size_t)b * CDIM * LSEQ + l;
    float acc[COT];
    #pragma unroll
    for (int i = 0; i < COT; i++) acc[i] = 0.f;
    const float4* ws4 = (const float4*)ws;
    for (int c = 0; c < 256; c += 4) {
        float x0 = xb[(size_t)(c + 0) * LSEQ];
        float x1 = xb[(size_t)(c + 1) * LSEQ];
        float x2 = xb[(size_t)(c + 2) * LSEQ];
        float x3 = xb[(size_t)(c + 3) * LSEQ];
        #pragma unroll
        for (int oo = 0; oo < COT; oo++) {
            float4 w = ws4[(oo * 256 + c) >> 2];
            acc[oo] = fadd(acc[oo], fmul(w.x, x0));
            acc[oo] = fadd(acc[oo], fmul(w.y, x1));
            acc[oo] = fadd(acc[oo], fmul(w.z, x2));
            acc[oo] = fadd(acc[oo], fmul(w.w, x3));
        }
    }
    for (int oo = 0; oo < COT; oo++)
        Y[((size_t)b * nrows + o0 + oo) * LSEQ + l] = acc[oo];
}

// ---------- fold (+ optional l2norm) --------------------------------
__global__ __launch_bounds__(256) void fold_np(const float* __restrict__ src,
        int srcRows, int row0, int donorm, float* __restrict__ dst) {
    int p = blockIdx.x * 256 + threadIdx.x;
    int bh = p >> 12, l = p & 4095;
    int b = bh >> 3, h = bh & 7;
    const float* sp = src + ((size_t)b * srcRows + row0 + h * 32) * LSEQ + l;
    float x[32];
    #pragma unroll
    for (int t = 0; t < 32; t++) x[t] = sp[(size_t)t * LSEQ];
    float4* dp4 = (float4*)(dst + (size_t)p * 32);
    if (donorm) {
        float ss = 0.f;
        #pragma unroll
        for (int t = 0; t < 32; t++) ss = fadd(ss, fmul(x[t], x[t]));
        float n = __fsqrt_rn(ss);
        float den = fmaxf(n, 1e-12f);
        #pragma unroll
        for (int t = 0; t < 32; t++) x[t] = __fdiv_rn(x[t], den);
    }
    #pragma unroll
    for (int t = 0; t < 8; t++)
        dp4[t] = make_float4(x[4*t], x[4*t+1], x[4*t+2], x[4*t+3]);
}

__global__ void copy32(const float* __restrict__ s, float* __restrict__ d, int n) {
    int i = blockIdx.x * 256 + threadIdx.x;
    if (i < n) d[i] = s[i];
}

// ---------- ||x||^2 per point (AVX-512 tree) ------------------------
__global__ __launch_bounds__(256) void xx_np(const float* __restrict__ pts,
        float* __restrict__ xx) {
    int p = blockIdx.x * 256 + threadIdx.x;
    const float4* x4 = (const float4*)(pts + (size_t)p * 32);
    float x[32];
    #pragma unroll
    for (int t = 0; t < 8; t++) {
        float4 f = x4[t];
        x[4*t] = f.x; x[4*t+1] = f.y; x[4*t+2] = f.z; x[4*t+3] = f.w;
    }
    float e[32];
    #pragma unroll
    for (int t = 0; t < 32; t++) e[t] = fmul(x[t], x[t]);
    xx[p] = sum32_np(e);
}

// ---------- ||c||^2 per centroid (initial) --------------------------
__global__ __launch_bounds__(256) void cc_np(const float* __restrict__ cent,
        float* __restrict__ cc) {
    int j = threadIdx.x;
    const float* c = cent + (size_t)j * 32;
    float e[32];
    #pragma unroll
    for (int t = 0; t < 32; t++) e[t] = fmul(c[t], c[t]);
    cc[j] = sum32_np(e);
}

// ---------- argmin + histogram: 128 threads x 2 points --------------
__global__ __launch_bounds__(128) void assign2_np(const float* __restrict__ pts,
        const float* __restrict__ xx, const float* __restrict__ cent,
        const float* __restrict__ cc, int* __restrict__ asn, int* __restrict__ hist) {
    __shared__ float sc[8192];
    __shared__ float scc[256];
    __shared__ int bins[256];
    int tid = threadIdx.x, c = blockIdx.x;
    {
        const float4* c4 = (const float4*)cent;
        float4* s4 = (float4*)sc;
        for (int i = tid; i < 2048; i += 128) s4[i] = c4[i];
    }
    scc[tid] = cc[tid]; scc[tid + 128] = cc[tid + 128];
    bins[tid] = 0; bins[tid + 128] = 0;
    __syncthreads();
    int p0 = c * 256 + tid, p1 = p0 + 128;
    float x0[32], x1[32];
    {
        const float4* pp0 = (const float4*)(pts + (size_t)p0 * 32);
        const float4* pp1 = (const float4*)(pts + (size_t)p1 * 32);
        #pragma unroll
        for (int t = 0; t < 8; t++) {
            float4 f = pp0[t];
            x0[4*t] = f.x; x0[4*t+1] = f.y; x0[4*t+2] = f.z; x0[4*t+3] = f.w;
            float4 g = pp1[t];
            x1[4*t] = g.x; x1[4*t+1] = g.y; x1[4*t+2] = g.z; x1[4*t+3] = g.w;
        }
    }
    float xp0 = xx[p0], xp1 = xx[p1];
    float bd0 = 3.4e38f, bd1 = 3.4e38f;
    int bj0 = 0, bj1 = 0;
    for (int j = 0; j < 256; j++) {
        const float4* cj = (const float4*)(sc + j * 32);
        float g0 = 0.f, g1 = 0.f;
        #pragma unroll
        for (int t = 0; t < 8; t++) {
            float4 w = cj[t];
            g0 = __builtin_fmaf(x0[4*t],   w.x, g0);
            g0 = __builtin_fmaf(x0[4*t+1], w.y, g0);
            g0 = __builtin_fmaf(x0[4*t+2], w.z, g0);
            g0 = __builtin_fmaf(x0[4*t+3], w.w, g0);
            g1 = __builtin_fmaf(x1[4*t],   w.x, g1);
            g1 = __builtin_fmaf(x1[4*t+1], w.y, g1);
            g1 = __builtin_fmaf(x1[4*t+2], w.z, g1);
            g1 = __builtin_fmaf(x1[4*t+3], w.w, g1);
        }
        float sj = scc[j];
        float d0 = fadd(fsub(xp0, fmul(2.f, g0)), sj);
        float d1 = fadd(fsub(xp1, fmul(2.f, g1)), sj);
        if (d0 < bd0) { bd0 = d0; bj0 = j; }
        if (d1 < bd1) { bd1 = d1; bj1 = j; }
    }
    asn[p0] = bj0; asn[p1] = bj1;
    atomicAdd(&bins[bj0], 1);
    atomicAdd(&bins[bj1], 1);
    __syncthreads();
    hist[c * 256 + tid] = bins[tid];
    hist[c * 256 + tid + 128] = bins[tid + 128];
}

// ---------- per-cluster prefix over chunks (one block per j) --------
__global__ __launch_bounds__(256) void scan_chunks(const int* __restrict__ hist,
        int* __restrict__ chunkbase, int* __restrict__ totals) {
    __shared__ int a[256];
    int j = blockIdx.x, c = threadIdx.x;
    a[c] = hist[c * 256 + j];
    __syncthreads();
    for (int d = 1; d < 256; d <<= 1) {
        int t = a[c];
        int u = (c >= d) ? a[c - d] : 0;
        __syncthreads();
        a[c] = t + u;
        __syncthreads();
    }
    chunkbase[c * 256 + j] = (c == 0) ? 0 : a[c - 1];
    if (c == 255) totals[j] = a[255];
}

// ---------- scatter (redundant cbase scan in LDS) -------------------
__global__ __launch_bounds__(256) void scatter_v3(const int* __restrict__ asn,
        const int* __restrict__ chunkbase, const int* __restrict__ totals,
        int* __restrict__ perm) {
    __shared__ int cb[256];
    __shared__ int a[256];
    int c = blockIdx.x, tid = threadIdx.x;
    cb[tid] = totals[tid];
    a[tid] = asn[c * 256 + tid];
    __syncthreads();
    if (tid == 0) {
        int run = 0;
        for (int u = 0; u < 256; u++) { int v = cb[u]; cb[u] = run; run += v; }
    }
    __syncthreads();
    int my = a[tid];
    int r = 0;
    for (int i = 0; i < tid; i++) r += (a[i] == my) ? 1 : 0;
    perm[cb[my] + chunkbase[c * 256 + my] + r] = c * 256 + tid;
}

// ---------- ordered sum + update + cc (redundant cbase) -------------
#define STILE 128
__global__ __launch_bounds__(256) void sumk_v3(const float* __restrict__ pts,
        const int* __restrict__ perm, const int* __restrict__ totals,
        float* __restrict__ cent, float* __restrict__ cc) {
    __shared__ float buf[2][STILE][32];
    __shared__ int cbs[256];
    int j = blockIdx.x, tid = threadIdx.x;
    cbs[tid] = totals[tid];
    __syncthreads();
    if (tid == 0) {
        int run = 0;
        for (int u = 0; u < 256; u++) { int v = cbs[u]; cbs[u] = run; run += v; }
    }
    __syncthreads();
    int base = cbs[j], n = totals[j];
    int t = tid & 31, r0 = tid >> 5;
    for (int r = r0; r < STILE; r += 8) {
        if (r < n) buf[0][r][t] = pts[(size_t)perm[base + r] * 32 + t];
    }
    __syncthreads();
    float s = 0.f;
    int b = 0;
    for (int i0 = 0; i0 < n; i0 += STILE, b ^= 1) {
        int nx = i0 + STILE;
        if (nx < n) {
            for (int r = r0; r < STILE; r += 8) {
                int g = nx + r;
                if (g < n) buf[b ^ 1][r][t] = pts[(size_t)perm[base + g] * 32 + t];
            }
        }
        if (tid < 32) {
            int m = n - i0; if (m > STILE) m = STILE;
            int i = 0;
            for (; i + 4 <= m; i += 4) {
                s = fadd(s, buf[b][i][tid]);
                s = fadd(s, buf[b][i + 1][tid]);
                s = fadd(s, buf[b][i + 2][tid]);
                s = fadd(s, buf[b][i + 3][tid]);
            }
            for (; i < m; i++) s = fadd(s, buf[b][i][tid]);
        }
        __syncthreads();
    }
    if (tid < 32) {
        float v;
        if (n > 0) {
            v = __fdiv_rn(s, (float)n);
            cent[(size_t)j * 32 + tid] = v;
        } else {
            v = cent[(size_t)j * 32 + tid];
        }
        // exact sum32_np tree via xor butterfly (verified R6/R7)
        float e = fmul(v, v);
        e = fadd(e, __shfl_xor(e, 16));
        e = fadd(e, __shfl_xor(e, 8));
        e = fadd(e, __shfl_xor(e, 4));
        e = fadd(e, __shfl_xor(e, 2));
        e = fadd(e, __shfl_xor(e, 1));
        if (tid == 0) cc[j] = e;
    }
}

// ---------- key assign + L1 dist: 128 thr x 2 pts, inline xx --------
__global__ __launch_bounds__(128) void kdist2_np(const float* __restrict__ pts,
        const float* __restrict__ cent, const float* __restrict__ cc,
        float* __restrict__ kd) {
    __shared__ float sc[8192];
    __shared__ float scc[256];
    int tid = threadIdx.x, c = blockIdx.x;
    {
        const float4* c4 = (const float4*)cent;
        float4* s4 = (float4*)sc;
        for (int i = tid; i < 2048; i += 128) s4[i] = c4[i];
    }
    scc[tid] = cc[tid]; scc[tid + 128] = cc[tid + 128];
    __syncthreads();
    int p0 = c * 256 + tid, p1 = p0 + 128;
    float x0[32], x1[32];
    {
        const float4* pp0 = (const float4*)(pts + (size_t)p0 * 32);
        const float4* pp1 = (const float4*)(pts + (size_t)p1 * 32);
        #pragma unroll
        for (int t = 0; t < 8; t++) {
            float4 f = pp0[t];
            x0[4*t] = f.x; x0[4*t+1] = f.y; x0[4*t+2] = f.z; x0[4*t+3] = f.w;
            float4 g = pp1[t];
            x1[4*t] = g.x; x1[4*t+1] = g.y; x1[4*t+2] = g.z; x1[4*t+3] = g.w;
        }
    }
    float xp0, xp1;
    {
        float e[32];
        #pragma unroll
        for (int t = 0; t < 32; t++) e[t] = fmul(x0[t], x0[t]);
        xp0 = sum32_np(e);
        #pragma unroll
        for (int t = 0; t < 32; t++) e[t] = fmul(x1[t], x1[t]);
        xp1 = sum32_np(e);
    }
    float bd0 = 3.4e38f, bd1 = 3.4e38f;
    int bj0 = 0, bj1 = 0;
    for (int j = 0; j < 256; j++) {
        const float4* cj = (const float4*)(sc + j * 32);
        float g0 = 0.f, g1 = 0.f;
        #pragma unroll
        for (int t = 0; t < 8; t++) {
            float4 w = cj[t];
            g0 = __builtin_fmaf(x0[4*t],   w.x, g0);
            g0 = __builtin_fmaf(x0[4*t+1], w.y, g0);
            g0 = __builtin_fmaf(x0[4*t+2], w.z, g0);
            g0 = __builtin_fmaf(x0[4*t+3], w.w, g0);
            g1 = __builtin_fmaf(x1[4*t],   w.x, g1);
            g1 = __builtin_fmaf(x1[4*t+1], w.y, g1);
            g1 = __builtin_fmaf(x1[4*t+2], w.z, g1);
            g1 = __builtin_fmaf(x1[4*t+3], w.w, g1);
        }
        float sj = scc[j];
        float d0 = fadd(fsub(xp0, fmul(2.f, g0)), sj);
        float d1 = fadd(fsub(xp1, fmul(2.f, g1)), sj);
        if (d0 < bd0) { bd0 = d0; bj0 = j; }
        if (d1 < bd1) { bd1 = d1; bj1 = j; }
    }
    {
        const float* cb = &sc[bj0 * 32];
        float e[32];
        #pragma unroll
        for (int t = 0; t < 32; t++) e[t] = fabsf(fsub(cb[t], x0[t]));
        kd[p0] = sum32_np(e);
    }
    {
        const float* cb = &sc[bj1 * 32];
        float e[32];
        #pragma unroll
        for (int t = 0; t < 32; t++) e[t] = fabsf(fsub(cb[t], x1[t]));
        kd[p1] = sum32_np(e);
    }
}

// ---------- top-256 via radix select (exact stable set) + gather ----
__global__ __launch_bounds__(256) void topk_v2(const float* __restrict__ kd,
        const float* __restrict__ k_t, const float* __restrict__ v_t,
        float* __restrict__ ksel, float* __restrict__ vsel) {
    __shared__ unsigned uv[4096];
    __shared__ int hist[256];
    __shared__ unsigned s_prefix;
    __shared__ int s_rem;
    __shared__ int sc1[256];
    __shared__ int out_src[256];
    int bh = blockIdx.x, tid = threadIdx.x;
    for (int i = tid; i < 4096; i += 256) uv[i] = __float_as_uint(kd[bh * 4096 + i]);
    if (tid == 0) { s_prefix = 0u; s_rem = 256; }
    out_src[tid] = 0;
    __syncthreads();
    for (int pass = 0; pass < 4; pass++) {
        int shift = 24 - 8 * pass;
        hist[tid] = 0;
        __syncthreads();
        unsigned pfx = s_prefix;
        for (int i = tid; i < 4096; i += 256) {
            unsigned u = uv[i];
            bool in = (pass == 0) || ((u >> (shift + 8)) == (pfx >> (shift + 8)));
            if (in) atomicAdd(&hist[(u >> shift) & 255], 1);
        }
        __syncthreads();
        if (tid == 0) {
            int rem = s_rem, cum = 0, b;
            for (b = 255; b >= 0; b--) {
                if (cum + hist[b] >= rem) break;
                cum += hist[b];
            }
            s_rem = rem - cum;
            s_prefix = s_prefix | ((unsigned)b << shift);
        }
        __syncthreads();
    }
    unsigned T = s_prefix;
    int r = s_rem;
    int base_i = tid * 16;
    int ec = 0;
    for (int q = 0; q < 16; q++) ec += (uv[base_i + q] == T) ? 1 : 0;
    sc1[tid] = ec;
    __syncthreads();
    for (int d = 1; d < 256; d <<= 1) {
        int t0 = sc1[tid];
        int u0 = (tid >= d) ? sc1[tid - d] : 0;
        __syncthreads();
        sc1[tid] = t0 + u0;
        __syncthreads();
    }
    int erank = (tid == 0) ? 0 : sc1[tid - 1];
    __syncthreads();
    bool incl[16];
    int ic = 0;
    for (int q = 0; q < 16; q++) {
        unsigned u = uv[base_i + q];
        bool inc;
        if (u > T) inc = true;
        else if (u == T) { inc = (erank < r); erank++; }
        else inc = false;
        incl[q] = inc;
        ic += inc ? 1 : 0;
    }
    sc1[tid] = ic;
    __syncthreads();
    for (int d = 1; d < 256; d <<= 1) {
        int t0 = sc1[tid];
        int u0 = (tid >= d) ? sc1[tid - d] : 0;
        __syncthreads();
        sc1[tid] = t0 + u0;
        __syncthreads();
    }
    int pos = (tid == 0) ? 0 : sc1[tid - 1];
    for (int q = 0; q < 16; q++) {
        if (incl[q]) out_src[pos++] = base_i + q;
    }
    __syncthreads();
    for (int e = tid; e < 256 * 32; e += 256) {
        int jj = e >> 5, t = e & 31;
        int src = out_src[jj];
        ksel[(size_t)bh * 8192 + e] = k_t[((size_t)bh * 4096 + src) * 32 + t];
        vsel[(size_t)bh * 8192 + e] = v_t[((size_t)bh * 4096 + src) * 32 + t];
    }
}

// ---------- attention v2: fixed-shift softmax (s<=1), lane-pair split
__global__ __launch_bounds__(256) void attn_v2(const float* __restrict__ q_t,
        const float* __restrict__ ksel, const float* __restrict__ vsel,
        float* __restrict__ out) {
    __shared__ float sk[8192];
    __shared__ float sv[8192];
    int bh = blockIdx.y, tid = threadIdx.x;
    {
        const float4* gk = (const float4*)(ksel + (size_t)bh * 8192);
        const float4* gv = (const float4*)(vsel + (size_t)bh * 8192);
        float4* k4s = (float4*)sk; float4* v4s = (float4*)sv;
        for (int i = tid; i < 2048; i += 256) { k4s[i] = gk[i]; v4s[i] = gv[i]; }
    }
    __syncthreads();
    int ql = tid >> 1, slice = tid & 1;
    int p = bh * 4096 + blockIdx.x * 128 + ql;
    float q[32];
    {
        const float4* qp = (const float4*)(q_t + (size_t)p * 32);
        #pragma unroll
        for (int t = 0; t < 8; t++) {
            float4 f = qp[t];
            q[4*t] = f.x; q[4*t+1] = f.y; q[4*t+2] = f.z; q[4*t+3] = f.w;
        }
    }
    float o[32];
    #pragma unroll
    for (int t = 0; t < 32; t++) o[t] = 0.f;
    float lsum = 0.f;
    const float4* k4 = (const float4*)sk;
    const float4* v4 = (const float4*)sv;
    int j0 = slice * 128;
    for (int j = j0; j < j0 + 128; j++) {
        float s = 0.f;
        #pragma unroll
        for (int t = 0; t < 8; t++) {
            float4 kf = k4[j * 8 + t];
            s += q[4*t]*kf.x + q[4*t+1]*kf.y + q[4*t+2]*kf.z + q[4*t+3]*kf.w;
        }
        float w = __expf(s - 1.0f);   // s <= 1 (unit vectors): no overflow
        lsum += w;
        #pragma unroll
        for (int t = 0; t < 8; t++) {
            float4 vf = v4[j * 8 + t];
            o[4*t]   += w * vf.x;
            o[4*t+1] += w * vf.y;
            o[4*t+2] += w * vf.z;
            o[4*t+3] += w * vf.w;
        }
    }
    #pragma unroll
    for (int t = 0; t < 32; t++) o[t] += __shfl_xor(o[t], 1);
    lsum += __shfl_xor(lsum, 1);
    if (slice == 0) {
        float inv = 1.f / lsum;
        float4* op = (float4*)(out + (size_t)p * 32);
        #pragma unroll
        for (int t = 0; t < 8; t++)
            op[t] = make_float4(o[4*t]*inv, o[4*t+1]*inv, o[4*t+2]*inv, o[4*t+3]*inv);
    }
}

// ---------- unfold (bh,L,32) -> (b,256,L) ---------------------------
__global__ __launch_bounds__(256) void unfold_kernel(const float* __restrict__ att,
        float* __restrict__ Fo) {
    __shared__ float tbuf[32][65];
    int bh = blockIdx.y, l0 = blockIdx.x * 64;
    int b = bh >> 3, h = bh & 7;
    int tid = threadIdx.x;
    #pragma unroll
    for (int r = 0; r < 8; r++) {
        int e = r * 256 + tid;
        int l = e >> 5, d = e & 31;
        tbuf[d][l] = att[((size_t)bh * 4096 + l0 + l) * 32 + d];
    }
    __syncthreads();
    #pragma unroll
    for (int r = 0; r < 8; r++) {
        int e = r * 256 + tid;
        int d = e >> 6, l = e & 63;
        Fo[((size_t)b * 256 + h * 32 + d) * LSEQ + l0 + l] = tbuf[d][l];
    }
}

// ---------- final LN + scale + residual (numpy orders) --------------
__global__ __launch_bounds__(64) void lnres_np(const float* __restrict__ x,
        const float* __restrict__ g, const float* __restrict__ bt,
        const float* __restrict__ gs, const float* __restrict__ qsrc,
        float* __restrict__ y) {
    int gid = blockIdx.x * 64 + threadIdx.x;
    int b = gid >> 12, l = gid & 4095;
    const float* xb = x + (size_t)b * CDIM * LSEQ + l;
    float s = 0.f;
    for (int c = 0; c < 256; c++) s = fadd(s, xb[(size_t)c * LSEQ]);
    float mean = __fdiv_rn(s, 256.f);
    float s2 = 0.f;
    for (int c = 0; c < 256; c++) {
        float d = fsub(xb[(size_t)c * LSEQ], mean);
        s2 = fadd(s2, fmul(d, d));
    }
    float var = __fdiv_rn(s2, 256.f);
    float den = fadd(__fsqrt_rn(var), 1e-6f);
    float scale = gs[0];
    const float* qb = qsrc + (size_t)b * CDIM * LSEQ + l;
    float* yb = y + (size_t)b * CDIM * LSEQ + l;
    for (int c = 0; c < 256; c++) {
        float d = fsub(xb[(size_t)c * LSEQ], mean);
        float r = fadd(__fdiv_rn(fmul(g[c], d), den), bt[c]);
        yb[(size_t)c * LSEQ] = fadd(fmul(scale, r), qb[(size_t)c * LSEQ]);
    }
}

// ==================================================================
extern "C" void kernel_launch(void* const* d_in, const int* in_sizes, int n_in,
                              void* d_out, int out_size, void* d_ws, size_t ws_size,
                              hipStream_t stream) {
    const float* qsrc   = (const float*)d_in[0];
    const float* ctx    = (const float*)d_in[1];
    const float* w_q    = (const float*)d_in[2];
    const float* w_kv   = (const float*)d_in[3];
    const float* w_out  = (const float*)d_in[4];
    const float* g_ctx  = (const float*)d_in[5];
    const float* b_ctx  = (const float*)d_in[6];
    const float* g_q    = (const float*)d_in[7];
    const float* b_q    = (const float*)d_in[8];
    const float* g_out  = (const float*)d_in[9];
    const float* b_out  = (const float*)d_in[10];
    const float* gs     = (const float*)d_in[11];

    char* base = (char*)d_ws;
    const size_t MB = 1024 * 1024;
    float* yln   = (float*)base;               // [0,8) LN out; later att
    float* att   = (float*)base;
    float* kvbuf = (float*)(base + 8 * MB);    // [8,24) kv conv; later y32 [8,16)
    float* y32   = (float*)(base + 8 * MB);
    float* qbuf  = (float*)(base + 24 * MB);   // [24,32) q conv; later Fo
    float* Fo    = (float*)(base + 24 * MB);
    float* q_t   = (float*)(base + 32 * MB);   // [32,40)
    float* k_t   = (float*)(base + 40 * MB);   // [40,48)
    float* v_t   = (float*)(base + 48 * MB);   // [48,56)
    char* SM = base + 56 * MB;
    float* xx_q      = (float*)(SM + 0);            // 256 KB
    float* cent      = (float*)(SM + 512 * 1024);   // 32 KB
    float* cc        = (float*)(SM + 576 * 1024);   // 1 KB
    int*   asn       = (int*)  (SM + 640 * 1024);   // 256 KB
    int*   totals    = (int*)  (SM + 896 * 1024);   // 1 KB
    int*   hist      = (int*)  (SM + 960 * 1024);   // 256 KB
    int*   chunkbase = (int*)  (SM + 1472 * 1024);  // 256 KB
    int*   perm      = (int*)  (SM + 1984 * 1024);  // 256 KB
    float* kd        = (float*)(SM + 2240 * 1024);  // 256 KB
    float* ksel      = (float*)(SM + 2496 * 1024);  // 512 KB
    float* vsel      = (float*)(SM + 3008 * 1024);  // 512 KB

    // context branch
    ln_np<<<128, 64, 0, stream>>>(ctx, g_ctx, b_ctx, yln);
    conv_t<32><<<dim3(16, 16, 2), 256, 0, stream>>>(w_kv, 0, yln, kvbuf, 512);
    fold_np<<<256, 256, 0, stream>>>(kvbuf, 512, 0, 1, k_t);
    fold_np<<<256, 256, 0, stream>>>(kvbuf, 512, 256, 0, v_t);
    // query branch
    ln_np<<<128, 64, 0, stream>>>(qsrc, g_q, b_q, yln);
    conv_t<16><<<dim3(16, 16, 2), 256, 0, stream>>>(w_q, 0, yln, qbuf, 256);
    fold_np<<<256, 256, 0, stream>>>(qbuf, 256, 0, 1, q_t);

    xx_np<<<256, 256, 0, stream>>>(q_t, xx_q);
    copy32<<<32, 256, 0, stream>>>(q_t, cent, 8192);
    cc_np<<<1, 256, 0, stream>>>(cent, cc);

    for (int it = 0; it < 10; it++) {
        assign2_np<<<256, 128, 0, stream>>>(q_t, xx_q, cent, cc, asn, hist);
        scan_chunks<<<256, 256, 0, stream>>>(hist, chunkbase, totals);
        scatter_v3<<<256, 256, 0, stream>>>(asn, chunkbase, totals, perm);
        sumk_v3<<<256, 256, 0, stream>>>(q_t, perm, totals, cent, cc);
    }

    kdist2_np<<<256, 128, 0, stream>>>(k_t, cent, cc, kd);
    topk_v2<<<16, 256, 0, stream>>>(kd, k_t, v_t, ksel, vsel);
    attn_v2<<<dim3(32, 16), 256, 0, stream>>>(q_t, ksel, vsel, att);
    unfold_kernel<<<dim3(64, 16), 256, 0, stream>>>(att, Fo);
    conv_t<16><<<dim3(16, 16, 2), 256, 0, stream>>>(w_out, 0, Fo, y32, 256);
    lnres_np<<<128, 64, 0, stream>>>(y32, g_out, b_out, gs, qsrc, (float*)d_out);
}

// Round 10
// 1114.687 us; speedup vs baseline: 2.9669x; 1.2304x over previous
//
#include <hip/hip_runtime.h>
#include <math.h>

#define CDIM 256
#define LSEQ 4096
#define NBH 16
#define NPTS 65536
#define KC 256

__device__ __forceinline__ float fadd(float a, float b){ return __fadd_rn(a,b); }
__device__ __forceinline__ float fmul(float a, float b){ return __fmul_rn(a,b); }
__device__ __forceinline__ float fsub(float a, float b){ return __fsub_rn(a,b); }

// numpy contiguous n=32 float32 sum, AVX-512 npyv path (verified R5)
__device__ __forceinline__ float sum32_np(const float* e){
    float l[16];
    #pragma unroll
    for (int j = 0; j < 16; j++) l[j] = fadd(e[j], e[j + 16]);
    float t3[8];
    #pragma unroll
    for (int j = 0; j < 8; j++) t3[j] = fadd(l[j], l[j + 8]);
    float t6[4];
    #pragma unroll
    for (int j = 0; j < 4; j++) t6[j] = fadd(t3[j], t3[j + 4]);
    return fadd(fadd(t6[0], t6[2]), fadd(t6[1], t6[3]));
}

// ---------- LayerNorm, numpy semantics (sequential over c) ----------
__global__ __launch_bounds__(64) void ln_np(const float* __restrict__ x,
        const float* __restrict__ g, const float* __restrict__ bt,
        float* __restrict__ y) {
    int gid = blockIdx.x * 64 + threadIdx.x;
    int b = gid >> 12, l = gid & 4095;
    const float* xb = x + (size_t)b * CDIM * LSEQ + l;
    float s = 0.f;
    for (int c = 0; c < 256; c++) s = fadd(s, xb[(size_t)c * LSEQ]);
    float mean = __fdiv_rn(s, 256.f);
    float s2 = 0.f;
    for (int c = 0; c < 256; c++) {
        float d = fsub(xb[(size_t)c * LSEQ], mean);
        s2 = fadd(s2, fmul(d, d));
    }
    float var = __fdiv_rn(s2, 256.f);
    float den = fadd(__fsqrt_rn(var), 1e-6f);
    float* yb = y + (size_t)b * CDIM * LSEQ + l;
    for (int c = 0; c < 256; c++) {
        float d = fsub(xb[(size_t)c * LSEQ], mean);
        yb[(size_t)c * LSEQ] = fadd(__fdiv_rn(fmul(g[c], d), den), bt[c]);
    }
}

// ---------- conv1x1, numpy einsum SOP semantics ---------------------
template<int COT>
__global__ __launch_bounds__(256) void conv_t(const float* __restrict__ W, int wrow0,
        const float* __restrict__ X, float* __restrict__ Y, int nrows) {
    __shared__ float ws[COT * 256];
    int tid = threadIdx.x;
    int l = blockIdx.x * 256 + tid;
    int o0 = blockIdx.y * COT;
    int b = blockIdx.z;
    {
        const float4* wb4 = (const float4*)(W + (size_t)(wrow0 + o0) * CDIM);
        float4* ws4 = (float4*)ws;
        for (int i = tid; i < COT * 64; i += 256) ws4[i] = wb4[i];
    }
    __syncthreads();
    const float* xb = X + (size_t)b * CDIM * LSEQ + l;
    float acc[COT];
    #pragma unroll
    for (int i = 0; i < COT; i++) acc[i] = 0.f;
    const float4* ws4 = (const float4*)ws;
    for (int c = 0; c < 256; c += 4) {
        float x0 = xb[(size_t)(c + 0) * LSEQ];
        float x1 = xb[(size_t)(c + 1) * LSEQ];
        float x2 = xb[(size_t)(c + 2) * LSEQ];
        float x3 = xb[(size_t)(c + 3) * LSEQ];
        #pragma unroll
        for (int oo = 0; oo < COT; oo++) {
            float4 w = ws4[(oo * 256 + c) >> 2];
            acc[oo] = fadd(acc[oo], fmul(w.x, x0));
            acc[oo] = fadd(acc[oo], fmul(w.y, x1));
            acc[oo] = fadd(acc[oo], fmul(w.z, x2));
            acc[oo] = fadd(acc[oo], fmul(w.w, x3));
        }
    }
    for (int oo = 0; oo < COT; oo++)
        Y[((size_t)b * nrows + o0 + oo) * LSEQ + l] = acc[oo];
}

// ---------- fold (+ optional l2norm) --------------------------------
__global__ __launch_bounds__(256) void fold_np(const float* __restrict__ src,
        int srcRows, int row0, int donorm, float* __restrict__ dst) {
    int p = blockIdx.x * 256 + threadIdx.x;
    int bh = p >> 12, l = p & 4095;
    int b = bh >> 3, h = bh & 7;
    const float* sp = src + ((size_t)b * srcRows + row0 + h * 32) * LSEQ + l;
    float x[32];
    #pragma unroll
    for (int t = 0; t < 32; t++) x[t] = sp[(size_t)t * LSEQ];
    float4* dp4 = (float4*)(dst + (size_t)p * 32);
    if (donorm) {
        float ss = 0.f;
        #pragma unroll
        for (int t = 0; t < 32; t++) ss = fadd(ss, fmul(x[t], x[t]));
        float n = __fsqrt_rn(ss);
        float den = fmaxf(n, 1e-12f);
        #pragma unroll
        for (int t = 0; t < 32; t++) x[t] = __fdiv_rn(x[t], den);
    }
    #pragma unroll
    for (int t = 0; t < 8; t++)
        dp4[t] = make_float4(x[4*t], x[4*t+1], x[4*t+2], x[4*t+3]);
}

__global__ void copy32(const float* __restrict__ s, float* __restrict__ d, int n) {
    int i = blockIdx.x * 256 + threadIdx.x;
    if (i < n) d[i] = s[i];
}

// ---------- ||x||^2 per point (AVX-512 tree) ------------------------
__global__ __launch_bounds__(256) void xx_np(const float* __restrict__ pts,
        float* __restrict__ xx) {
    int p = blockIdx.x * 256 + threadIdx.x;
    const float4* x4 = (const float4*)(pts + (size_t)p * 32);
    float x[32];
    #pragma unroll
    for (int t = 0; t < 8; t++) {
        float4 f = x4[t];
        x[4*t] = f.x; x[4*t+1] = f.y; x[4*t+2] = f.z; x[4*t+3] = f.w;
    }
    float e[32];
    #pragma unroll
    for (int t = 0; t < 32; t++) e[t] = fmul(x[t], x[t]);
    xx[p] = sum32_np(e);
}

// ---------- ||c||^2 per centroid (initial) --------------------------
__global__ __launch_bounds__(256) void cc_np(const float* __restrict__ cent,
        float* __restrict__ cc) {
    int j = threadIdx.x;
    const float* c = cent + (size_t)j * 32;
    float e[32];
    #pragma unroll
    for (int t = 0; t < 32; t++) e[t] = fmul(c[t], c[t]);
    cc[j] = sum32_np(e);
}

// ---------- argmin + histogram: half-split, 2 thr/point -------------
// grid 512 x 256: block = 128 points; lane pair splits clusters 0-127/128-255.
// Merge is comparison-only (strict <) -> bit-identical to sequential argmin.
__global__ __launch_bounds__(256) void assign_half(const float* __restrict__ pts,
        const float* __restrict__ xx, const float* __restrict__ cent,
        const float* __restrict__ cc, int* __restrict__ asn, int* __restrict__ hist) {
    __shared__ float sc[8192];
    __shared__ float scc[256];
    __shared__ int bins[256];
    int tid = threadIdx.x, c = blockIdx.x;
    {
        const float4* c4 = (const float4*)cent;
        float4* s4 = (float4*)sc;
        for (int i = tid; i < 2048; i += 256) s4[i] = c4[i];
    }
    scc[tid] = cc[tid];
    bins[tid] = 0;
    __syncthreads();
    int pl = tid >> 1, half = tid & 1;
    int p = c * 128 + pl;
    float x[32];
    {
        const float4* pp = (const float4*)(pts + (size_t)p * 32);
        #pragma unroll
        for (int t = 0; t < 8; t++) {
            float4 f = pp[t];
            x[4*t] = f.x; x[4*t+1] = f.y; x[4*t+2] = f.z; x[4*t+3] = f.w;
        }
    }
    float xp = xx[p];
    float bd = 3.4e38f; int bj = 0;
    int jbase = half * 128;
    for (int jj = 0; jj < 128; jj++) {
        int j = jbase + jj;
        const float4* cj = (const float4*)(sc + j * 32);
        float g = 0.f;
        #pragma unroll
        for (int t = 0; t < 8; t++) {
            float4 w = cj[t];
            g = __builtin_fmaf(x[4*t],   w.x, g);
            g = __builtin_fmaf(x[4*t+1], w.y, g);
            g = __builtin_fmaf(x[4*t+2], w.z, g);
            g = __builtin_fmaf(x[4*t+3], w.w, g);
        }
        float d = fadd(fsub(xp, fmul(2.f, g)), scc[j]);
        if (d < bd) { bd = d; bj = j; }
    }
    float bd1 = __shfl_xor(bd, 1);
    int   bj1 = __shfl_xor(bj, 1);
    if (half == 0) {
        if (bd1 < bd) { bd = bd1; bj = bj1; }
        asn[p] = bj;
        atomicAdd(&bins[bj], 1);
    }
    __syncthreads();
    hist[c * 256 + tid] = bins[tid];
}

// ---------- per-cluster prefix over 512 chunks (pair/thread) --------
__global__ __launch_bounds__(256) void scan_chunks512(const int* __restrict__ hist,
        int* __restrict__ chunkbase, int* __restrict__ totals) {
    __shared__ int a[256];
    int j = blockIdx.x, t = threadIdx.x;
    int h0 = hist[(size_t)(2 * t) * 256 + j];
    int h1 = hist[(size_t)(2 * t + 1) * 256 + j];
    a[t] = h0 + h1;
    __syncthreads();
    for (int d = 1; d < 256; d <<= 1) {
        int v = a[t];
        int u = (t >= d) ? a[t - d] : 0;
        __syncthreads();
        a[t] = v + u;
        __syncthreads();
    }
    int excl = (t == 0) ? 0 : a[t - 1];
    chunkbase[(size_t)(2 * t) * 256 + j] = excl;
    chunkbase[(size_t)(2 * t + 1) * 256 + j] = excl + h0;
    if (t == 255) totals[j] = a[255];
}

// ---------- scatter: parallel cbase scan + stable rank --------------
__global__ __launch_bounds__(256) void scatter_v4(const int* __restrict__ asn,
        const int* __restrict__ chunkbase, const int* __restrict__ totals,
        int* __restrict__ perm) {
    __shared__ int cb[256];
    __shared__ int al[128];
    int c = blockIdx.x, tid = threadIdx.x;
    cb[tid] = totals[tid];
    if (tid < 128) al[tid] = asn[c * 128 + tid];
    __syncthreads();
    for (int d = 1; d < 256; d <<= 1) {
        int v = cb[tid];
        int u = (tid >= d) ? cb[tid - d] : 0;
        __syncthreads();
        cb[tid] = v + u;
        __syncthreads();
    }
    if (tid < 128) {
        int my = al[tid];
        int base = (my == 0) ? 0 : cb[my - 1];
        int r = 0;
        for (int i = 0; i < tid; i++) r += (al[i] == my) ? 1 : 0;
        perm[base + chunkbase[(size_t)c * 256 + my] + r] = c * 128 + tid;
    }
}

// ---------- ordered sum + update + cc (parallel cbase scan) ---------
#define STILE 128
__global__ __launch_bounds__(256) void sumk_v4(const float* __restrict__ pts,
        const int* __restrict__ perm, const int* __restrict__ totals,
        float* __restrict__ cent, float* __restrict__ cc) {
    __shared__ int cb[256];
    __shared__ float buf[2][STILE][32];
    int j = blockIdx.x, tid = threadIdx.x;
    cb[tid] = totals[tid];
    __syncthreads();
    for (int d = 1; d < 256; d <<= 1) {
        int v = cb[tid];
        int u = (tid >= d) ? cb[tid - d] : 0;
        __syncthreads();
        cb[tid] = v + u;
        __syncthreads();
    }
    int base = (j == 0) ? 0 : cb[j - 1];
    int n = totals[j];
    int t = tid & 31, r0 = tid >> 5;
    for (int r = r0; r < STILE; r += 8) {
        if (r < n) buf[0][r][t] = pts[(size_t)perm[base + r] * 32 + t];
    }
    __syncthreads();
    float s = 0.f;
    int b = 0;
    for (int i0 = 0; i0 < n; i0 += STILE, b ^= 1) {
        int nx = i0 + STILE;
        if (nx < n) {
            for (int r = r0; r < STILE; r += 8) {
                int g = nx + r;
                if (g < n) buf[b ^ 1][r][t] = pts[(size_t)perm[base + g] * 32 + t];
            }
        }
        if (tid < 32) {
            int m = n - i0; if (m > STILE) m = STILE;
            int i = 0;
            for (; i + 4 <= m; i += 4) {
                s = fadd(s, buf[b][i][tid]);
                s = fadd(s, buf[b][i + 1][tid]);
                s = fadd(s, buf[b][i + 2][tid]);
                s = fadd(s, buf[b][i + 3][tid]);
            }
            for (; i < m; i++) s = fadd(s, buf[b][i][tid]);
        }
        __syncthreads();
    }
    if (tid < 32) {
        float v;
        if (n > 0) {
            v = __fdiv_rn(s, (float)n);
            cent[(size_t)j * 32 + tid] = v;
        } else {
            v = cent[(size_t)j * 32 + tid];
        }
        // exact sum32_np tree via xor butterfly (verified R6/R7)
        float e = fmul(v, v);
        e = fadd(e, __shfl_xor(e, 16));
        e = fadd(e, __shfl_xor(e, 8));
        e = fadd(e, __shfl_xor(e, 4));
        e = fadd(e, __shfl_xor(e, 2));
        e = fadd(e, __shfl_xor(e, 1));
        if (tid == 0) cc[j] = e;
    }
}

// ---------- key assign + L1: half-split, inline xx ------------------
__global__ __launch_bounds__(256) void kdist_half(const float* __restrict__ pts,
        const float* __restrict__ cent, const float* __restrict__ cc,
        float* __restrict__ kd) {
    __shared__ float sc[8192];
    __shared__ float scc[256];
    int tid = threadIdx.x, c = blockIdx.x;
    {
        const float4* c4 = (const float4*)cent;
        float4* s4 = (float4*)sc;
        for (int i = tid; i < 2048; i += 256) s4[i] = c4[i];
    }
    scc[tid] = cc[tid];
    __syncthreads();
    int pl = tid >> 1, half = tid & 1;
    int p = c * 128 + pl;
    float x[32];
    {
        const float4* pp = (const float4*)(pts + (size_t)p * 32);
        #pragma unroll
        for (int t = 0; t < 8; t++) {
            float4 f = pp[t];
            x[4*t] = f.x; x[4*t+1] = f.y; x[4*t+2] = f.z; x[4*t+3] = f.w;
        }
    }
    float xp;
    {
        float e[32];
        #pragma unroll
        for (int t = 0; t < 32; t++) e[t] = fmul(x[t], x[t]);
        xp = sum32_np(e);   // identical bits to xx_np
    }
    float bd = 3.4e38f; int bj = 0;
    int jbase = half * 128;
    for (int jj = 0; jj < 128; jj++) {
        int j = jbase + jj;
        const float4* cj = (const float4*)(sc + j * 32);
        float g = 0.f;
        #pragma unroll
        for (int t = 0; t < 8; t++) {
            float4 w = cj[t];
            g = __builtin_fmaf(x[4*t],   w.x, g);
            g = __builtin_fmaf(x[4*t+1], w.y, g);
            g = __builtin_fmaf(x[4*t+2], w.z, g);
            g = __builtin_fmaf(x[4*t+3], w.w, g);
        }
        float d = fadd(fsub(xp, fmul(2.f, g)), scc[j]);
        if (d < bd) { bd = d; bj = j; }
    }
    float bd1 = __shfl_xor(bd, 1);
    int   bj1 = __shfl_xor(bj, 1);
    if (half == 0) {
        if (bd1 < bd) { bd = bd1; bj = bj1; }
        const float* cb = &sc[bj * 32];
        float e[32];
        #pragma unroll
        for (int t = 0; t < 32; t++) e[t] = fabsf(fsub(cb[t], x[t]));
        kd[p] = sum32_np(e);
    }
}

// ---------- top-256 via radix select (exact stable set) + gather ----
__global__ __launch_bounds__(256) void topk_v2(const float* __restrict__ kd,
        const float* __restrict__ k_t, const float* __restrict__ v_t,
        float* __restrict__ ksel, float* __restrict__ vsel) {
    __shared__ unsigned uv[4096];
    __shared__ int hist[256];
    __shared__ unsigned s_prefix;
    __shared__ int s_rem;
    __shared__ int sc1[256];
    __shared__ int out_src[256];
    int bh = blockIdx.x, tid = threadIdx.x;
    for (int i = tid; i < 4096; i += 256) uv[i] = __float_as_uint(kd[bh * 4096 + i]);
    if (tid == 0) { s_prefix = 0u; s_rem = 256; }
    out_src[tid] = 0;
    __syncthreads();
    for (int pass = 0; pass < 4; pass++) {
        int shift = 24 - 8 * pass;
        hist[tid] = 0;
        __syncthreads();
        unsigned pfx = s_prefix;
        for (int i = tid; i < 4096; i += 256) {
            unsigned u = uv[i];
            bool in = (pass == 0) || ((u >> (shift + 8)) == (pfx >> (shift + 8)));
            if (in) atomicAdd(&hist[(u >> shift) & 255], 1);
        }
        __syncthreads();
        if (tid == 0) {
            int rem = s_rem, cum = 0, b;
            for (b = 255; b >= 0; b--) {
                if (cum + hist[b] >= rem) break;
                cum += hist[b];
            }
            s_rem = rem - cum;
            s_prefix = s_prefix | ((unsigned)b << shift);
        }
        __syncthreads();
    }
    unsigned T = s_prefix;
    int r = s_rem;
    int base_i = tid * 16;
    int ec = 0;
    for (int q = 0; q < 16; q++) ec += (uv[base_i + q] == T) ? 1 : 0;
    sc1[tid] = ec;
    __syncthreads();
    for (int d = 1; d < 256; d <<= 1) {
        int t0 = sc1[tid];
        int u0 = (tid >= d) ? sc1[tid - d] : 0;
        __syncthreads();
        sc1[tid] = t0 + u0;
        __syncthreads();
    }
    int erank = (tid == 0) ? 0 : sc1[tid - 1];
    __syncthreads();
    bool incl[16];
    int ic = 0;
    for (int q = 0; q < 16; q++) {
        unsigned u = uv[base_i + q];
        bool inc;
        if (u > T) inc = true;
        else if (u == T) { inc = (erank < r); erank++; }
        else inc = false;
        incl[q] = inc;
        ic += inc ? 1 : 0;
    }
    sc1[tid] = ic;
    __syncthreads();
    for (int d = 1; d < 256; d <<= 1) {
        int t0 = sc1[tid];
        int u0 = (tid >= d) ? sc1[tid - d] : 0;
        __syncthreads();
        sc1[tid] = t0 + u0;
        __syncthreads();
    }
    int pos = (tid == 0) ? 0 : sc1[tid - 1];
    for (int q = 0; q < 16; q++) {
        if (incl[q]) out_src[pos++] = base_i + q;
    }
    __syncthreads();
    for (int e = tid; e < 256 * 32; e += 256) {
        int jj = e >> 5, t = e & 31;
        int src = out_src[jj];
        ksel[(size_t)bh * 8192 + e] = k_t[((size_t)bh * 4096 + src) * 32 + t];
        vsel[(size_t)bh * 8192 + e] = v_t[((size_t)bh * 4096 + src) * 32 + t];
    }
}

// ---------- attention v2: fixed-shift softmax (s<=1), lane-pair split
__global__ __launch_bounds__(256) void attn_v2(const float* __restrict__ q_t,
        const float* __restrict__ ksel, const float* __restrict__ vsel,
        float* __restrict__ out) {
    __shared__ float sk[8192];
    __shared__ float sv[8192];
    int bh = blockIdx.y, tid = threadIdx.x;
    {
        const float4* gk = (const float4*)(ksel + (size_t)bh * 8192);
        const float4* gv = (const float4*)(vsel + (size_t)bh * 8192);
        float4* k4s = (float4*)sk; float4* v4s = (float4*)sv;
        for (int i = tid; i < 2048; i += 256) { k4s[i] = gk[i]; v4s[i] = gv[i]; }
    }
    __syncthreads();
    int ql = tid >> 1, slice = tid & 1;
    int p = bh * 4096 + blockIdx.x * 128 + ql;
    float q[32];
    {
        const float4* qp = (const float4*)(q_t + (size_t)p * 32);
        #pragma unroll
        for (int t = 0; t < 8; t++) {
            float4 f = qp[t];
            q[4*t] = f.x; q[4*t+1] = f.y; q[4*t+2] = f.z; q[4*t+3] = f.w;
        }
    }
    float o[32];
    #pragma unroll
    for (int t = 0; t < 32; t++) o[t] = 0.f;
    float lsum = 0.f;
    const float4* k4 = (const float4*)sk;
    const float4* v4 = (const float4*)sv;
    int j0 = slice * 128;
    for (int j = j0; j < j0 + 128; j++) {
        float s = 0.f;
        #pragma unroll
        for (int t = 0; t < 8; t++) {
            float4 kf = k4[j * 8 + t];
            s += q[4*t]*kf.x + q[4*t+1]*kf.y + q[4*t+2]*kf.z + q[4*t+3]*kf.w;
        }
        float w = __expf(s - 1.0f);   // s <= 1 (unit vectors): no overflow
        lsum += w;
        #pragma unroll
        for (int t = 0; t < 8; t++) {
            float4 vf = v4[j * 8 + t];
            o[4*t]   += w * vf.x;
            o[4*t+1] += w * vf.y;
            o[4*t+2] += w * vf.z;
            o[4*t+3] += w * vf.w;
        }
    }
    #pragma unroll
    for (int t = 0; t < 32; t++) o[t] += __shfl_xor(o[t], 1);
    lsum += __shfl_xor(lsum, 1);
    if (slice == 0) {
        float inv = 1.f / lsum;
        float4* op = (float4*)(out + (size_t)p * 32);
        #pragma unroll
        for (int t = 0; t < 8; t++)
            op[t] = make_float4(o[4*t]*inv, o[4*t+1]*inv, o[4*t+2]*inv, o[4*t+3]*inv);
    }
}

// ---------- unfold (bh,L,32) -> (b,256,L) ---------------------------
__global__ __launch_bounds__(256) void unfold_kernel(const float* __restrict__ att,
        float* __restrict__ Fo) {
    __shared__ float tbuf[32][65];
    int bh = blockIdx.y, l0 = blockIdx.x * 64;
    int b = bh >> 3, h = bh & 7;
    int tid = threadIdx.x;
    #pragma unroll
    for (int r = 0; r < 8; r++) {
        int e = r * 256 + tid;
        int l = e >> 5, d = e & 31;
        tbuf[d][l] = att[((size_t)bh * 4096 + l0 + l) * 32 + d];
    }
    __syncthreads();
    #pragma unroll
    for (int r = 0; r < 8; r++) {
        int e = r * 256 + tid;
        int d = e >> 6, l = e & 63;
        Fo[((size_t)b * 256 + h * 32 + d) * LSEQ + l0 + l] = tbuf[d][l];
    }
}

// ---------- final LN + scale + residual (numpy orders) --------------
__global__ __launch_bounds__(64) void lnres_np(const float* __restrict__ x,
        const float* __restrict__ g, const float* __restrict__ bt,
        const float* __restrict__ gs, const float* __restrict__ qsrc,
        float* __restrict__ y) {
    int gid = blockIdx.x * 64 + threadIdx.x;
    int b = gid >> 12, l = gid & 4095;
    const float* xb = x + (size_t)b * CDIM * LSEQ + l;
    float s = 0.f;
    for (int c = 0; c < 256; c++) s = fadd(s, xb[(size_t)c * LSEQ]);
    float mean = __fdiv_rn(s, 256.f);
    float s2 = 0.f;
    for (int c = 0; c < 256; c++) {
        float d = fsub(xb[(size_t)c * LSEQ], mean);
        s2 = fadd(s2, fmul(d, d));
    }
    float var = __fdiv_rn(s2, 256.f);
    float den = fadd(__fsqrt_rn(var), 1e-6f);
    float scale = gs[0];
    const float* qb = qsrc + (size_t)b * CDIM * LSEQ + l;
    float* yb = y + (size_t)b * CDIM * LSEQ + l;
    for (int c = 0; c < 256; c++) {
        float d = fsub(xb[(size_t)c * LSEQ], mean);
        float r = fadd(__fdiv_rn(fmul(g[c], d), den), bt[c]);
        yb[(size_t)c * LSEQ] = fadd(fmul(scale, r), qb[(size_t)c * LSEQ]);
    }
}

// ==================================================================
extern "C" void kernel_launch(void* const* d_in, const int* in_sizes, int n_in,
                              void* d_out, int out_size, void* d_ws, size_t ws_size,
                              hipStream_t stream) {
    const float* qsrc   = (const float*)d_in[0];
    const float* ctx    = (const float*)d_in[1];
    const float* w_q    = (const float*)d_in[2];
    const float* w_kv   = (const float*)d_in[3];
    const float* w_out  = (const float*)d_in[4];
    const float* g_ctx  = (const float*)d_in[5];
    const float* b_ctx  = (const float*)d_in[6];
    const float* g_q    = (const float*)d_in[7];
    const float* b_q    = (const float*)d_in[8];
    const float* g_out  = (const float*)d_in[9];
    const float* b_out  = (const float*)d_in[10];
    const float* gs     = (const float*)d_in[11];

    char* base = (char*)d_ws;
    const size_t MB = 1024 * 1024;
    float* yln   = (float*)base;               // [0,8) LN out; later att
    float* att   = (float*)base;
    float* kvbuf = (float*)(base + 8 * MB);    // [8,24) kv conv; later y32 [8,16)
    float* y32   = (float*)(base + 8 * MB);
    float* qbuf  = (float*)(base + 24 * MB);   // [24,32) q conv; later Fo
    float* Fo    = (float*)(base + 24 * MB);
    float* q_t   = (float*)(base + 32 * MB);   // [32,40)
    float* k_t   = (float*)(base + 40 * MB);   // [40,48)
    float* v_t   = (float*)(base + 48 * MB);   // [48,56)
    char* SM = base + 56 * MB;
    float* xx_q      = (float*)(SM + 0);            // 256 KB
    float* cent      = (float*)(SM + 512 * 1024);   // 32 KB
    float* cc        = (float*)(SM + 576 * 1024);   // 1 KB
    int*   totals    = (int*)  (SM + 640 * 1024);   // 1 KB
    int*   asn       = (int*)  (SM + 704 * 1024);   // 256 KB
    int*   hist      = (int*)  (SM + 960 * 1024);   // 512 KB (512 chunks)
    int*   chunkbase = (int*)  (SM + 1472 * 1024);  // 512 KB
    int*   perm      = (int*)  (SM + 1984 * 1024);  // 256 KB
    float* kd        = (float*)(SM + 2240 * 1024);  // 256 KB
    float* ksel      = (float*)(SM + 2496 * 1024);  // 512 KB
    float* vsel      = (float*)(SM + 3008 * 1024);  // 512 KB

    // context branch
    ln_np<<<128, 64, 0, stream>>>(ctx, g_ctx, b_ctx, yln);
    conv_t<16><<<dim3(16, 32, 2), 256, 0, stream>>>(w_kv, 0, yln, kvbuf, 512);
    fold_np<<<256, 256, 0, stream>>>(kvbuf, 512, 0, 1, k_t);
    fold_np<<<256, 256, 0, stream>>>(kvbuf, 512, 256, 0, v_t);
    // query branch
    ln_np<<<128, 64, 0, stream>>>(qsrc, g_q, b_q, yln);
    conv_t<8><<<dim3(16, 32, 2), 256, 0, stream>>>(w_q, 0, yln, qbuf, 256);
    fold_np<<<256, 256, 0, stream>>>(qbuf, 256, 0, 1, q_t);

    xx_np<<<256, 256, 0, stream>>>(q_t, xx_q);
    copy32<<<32, 256, 0, stream>>>(q_t, cent, 8192);
    cc_np<<<1, 256, 0, stream>>>(cent, cc);

    for (int it = 0; it < 10; it++) {
        assign_half<<<512, 256, 0, stream>>>(q_t, xx_q, cent, cc, asn, hist);
        scan_chunks512<<<256, 256, 0, stream>>>(hist, chunkbase, totals);
        scatter_v4<<<512, 256, 0, stream>>>(asn, chunkbase, totals, perm);
        sumk_v4<<<256, 256, 0, stream>>>(q_t, perm, totals, cent, cc);
    }

    kdist_half<<<512, 256, 0, stream>>>(k_t, cent, cc, kd);
    topk_v2<<<16, 256, 0, stream>>>(kd, k_t, v_t, ksel, vsel);
    attn_v2<<<dim3(32, 16), 256, 0, stream>>>(q_t, ksel, vsel, att);
    unfold_kernel<<<dim3(64, 16), 256, 0, stream>>>(att, Fo);
    conv_t<8><<<dim3(16, 32, 2), 256, 0, stream>>>(w_out, 0, Fo, y32, 256);
    lnres_np<<<128, 64, 0, stream>>>(y32, g_out, b_out, gs, qsrc, (float*)d_out);
}

// Round 11
// 1032.527 us; speedup vs baseline: 3.2030x; 1.0796x over previous
//
#include <hip/hip_runtime.h>
#include <math.h>

#define CDIM 256
#define LSEQ 4096
#define NBH 16
#define NPTS 65536
#define KC 256

__device__ __forceinline__ float fadd(float a, float b){ return __fadd_rn(a,b); }
__device__ __forceinline__ float fmul(float a, float b){ return __fmul_rn(a,b); }
__device__ __forceinline__ float fsub(float a, float b){ return __fsub_rn(a,b); }

// numpy contiguous n=32 float32 sum, AVX-512 npyv path (verified R5)
__device__ __forceinline__ float sum32_np(const float* e){
    float l[16];
    #pragma unroll
    for (int j = 0; j < 16; j++) l[j] = fadd(e[j], e[j + 16]);
    float t3[8];
    #pragma unroll
    for (int j = 0; j < 8; j++) t3[j] = fadd(l[j], l[j + 8]);
    float t6[4];
    #pragma unroll
    for (int j = 0; j < 4; j++) t6[j] = fadd(t3[j], t3[j + 4]);
    return fadd(fadd(t6[0], t6[2]), fadd(t6[1], t6[3]));
}

// ---------- LayerNorm, numpy semantics (sequential over c) ----------
__global__ __launch_bounds__(64) void ln_np(const float* __restrict__ x,
        const float* __restrict__ g, const float* __restrict__ bt,
        float* __restrict__ y) {
    int gid = blockIdx.x * 64 + threadIdx.x;
    int b = gid >> 12, l = gid & 4095;
    const float* xb = x + (size_t)b * CDIM * LSEQ + l;
    float s = 0.f;
    for (int c = 0; c < 256; c++) s = fadd(s, xb[(size_t)c * LSEQ]);
    float mean = __fdiv_rn(s, 256.f);
    float s2 = 0.f;
    for (int c = 0; c < 256; c++) {
        float d = fsub(xb[(size_t)c * LSEQ], mean);
        s2 = fadd(s2, fmul(d, d));
    }
    float var = __fdiv_rn(s2, 256.f);
    float den = fadd(__fsqrt_rn(var), 1e-6f);
    float* yb = y + (size_t)b * CDIM * LSEQ + l;
    for (int c = 0; c < 256; c++) {
        float d = fsub(xb[(size_t)c * LSEQ], mean);
        yb[(size_t)c * LSEQ] = fadd(__fdiv_rn(fmul(g[c], d), den), bt[c]);
    }
}

// ---------- conv1x1, SOP semantics, NL l-positions per thread -------
template<int COT, int NL>
__global__ __launch_bounds__(256) void conv_nl(const float* __restrict__ W, int wrow0,
        const float* __restrict__ X, float* __restrict__ Y, int nrows) {
    __shared__ float ws[COT * 256];
    int tid = threadIdx.x;
    int l0 = blockIdx.x * (256 * NL) + tid;
    int o0 = blockIdx.y * COT;
    int b = blockIdx.z;
    {
        const float4* wb4 = (const float4*)(W + (size_t)(wrow0 + o0) * CDIM);
        float4* ws4 = (float4*)ws;
        for (int i = tid; i < COT * 64; i += 256) ws4[i] = wb4[i];
    }
    __syncthreads();
    const float* xb = X + (size_t)b * CDIM * LSEQ;
    float acc[COT][NL];
    #pragma unroll
    for (int oo = 0; oo < COT; oo++)
        #pragma unroll
        for (int i = 0; i < NL; i++) acc[oo][i] = 0.f;
    const float4* ws4 = (const float4*)ws;
    for (int c = 0; c < 256; c += 4) {
        float xv[NL][4];
        #pragma unroll
        for (int i = 0; i < NL; i++) {
            #pragma unroll
            for (int k = 0; k < 4; k++)
                xv[i][k] = xb[(size_t)(c + k) * LSEQ + l0 + i * 256];
        }
        #pragma unroll
        for (int oo = 0; oo < COT; oo++) {
            float4 w = ws4[(oo * 256 + c) >> 2];
            #pragma unroll
            for (int i = 0; i < NL; i++) {
                acc[oo][i] = fadd(acc[oo][i], fmul(w.x, xv[i][0]));
                acc[oo][i] = fadd(acc[oo][i], fmul(w.y, xv[i][1]));
                acc[oo][i] = fadd(acc[oo][i], fmul(w.z, xv[i][2]));
                acc[oo][i] = fadd(acc[oo][i], fmul(w.w, xv[i][3]));
            }
        }
    }
    #pragma unroll
    for (int oo = 0; oo < COT; oo++)
        #pragma unroll
        for (int i = 0; i < NL; i++)
            Y[((size_t)b * nrows + o0 + oo) * LSEQ + l0 + i * 256] = acc[oo][i];
}

// ---------- fold (+ optional l2norm) --------------------------------
__global__ __launch_bounds__(256) void fold_np(const float* __restrict__ src,
        int srcRows, int row0, int donorm, float* __restrict__ dst) {
    int p = blockIdx.x * 256 + threadIdx.x;
    int bh = p >> 12, l = p & 4095;
    int b = bh >> 3, h = bh & 7;
    const float* sp = src + ((size_t)b * srcRows + row0 + h * 32) * LSEQ + l;
    float x[32];
    #pragma unroll
    for (int t = 0; t < 32; t++) x[t] = sp[(size_t)t * LSEQ];
    float4* dp4 = (float4*)(dst + (size_t)p * 32);
    if (donorm) {
        float ss = 0.f;
        #pragma unroll
        for (int t = 0; t < 32; t++) ss = fadd(ss, fmul(x[t], x[t]));
        float n = __fsqrt_rn(ss);
        float den = fmaxf(n, 1e-12f);
        #pragma unroll
        for (int t = 0; t < 32; t++) x[t] = __fdiv_rn(x[t], den);
    }
    #pragma unroll
    for (int t = 0; t < 8; t++)
        dp4[t] = make_float4(x[4*t], x[4*t+1], x[4*t+2], x[4*t+3]);
}

__global__ void copy32(const float* __restrict__ s, float* __restrict__ d, int n) {
    int i = blockIdx.x * 256 + threadIdx.x;
    if (i < n) d[i] = s[i];
}

// ---------- ||x||^2 per point (AVX-512 tree) ------------------------
__global__ __launch_bounds__(256) void xx_np(const float* __restrict__ pts,
        float* __restrict__ xx) {
    int p = blockIdx.x * 256 + threadIdx.x;
    const float4* x4 = (const float4*)(pts + (size_t)p * 32);
    float x[32];
    #pragma unroll
    for (int t = 0; t < 8; t++) {
        float4 f = x4[t];
        x[4*t] = f.x; x[4*t+1] = f.y; x[4*t+2] = f.z; x[4*t+3] = f.w;
    }
    float e[32];
    #pragma unroll
    for (int t = 0; t < 32; t++) e[t] = fmul(x[t], x[t]);
    xx[p] = sum32_np(e);
}

// ---------- ||c||^2 per centroid (initial) --------------------------
__global__ __launch_bounds__(256) void cc_np(const float* __restrict__ cent,
        float* __restrict__ cc) {
    int j = threadIdx.x;
    const float* c = cent + (size_t)j * 32;
    float e[32];
    #pragma unroll
    for (int t = 0; t < 32; t++) e[t] = fmul(c[t], c[t]);
    cc[j] = sum32_np(e);
}

// ---------- argmin+hist: 2 points/thread x half clusters ------------
// grid 256 x 256: block = 256 points. Lane pair: half 0/1 of clusters.
// Strict-< merge == sequential argmin 0..255 (bit-exact).
__global__ __launch_bounds__(256) void assign2_half(const float* __restrict__ pts,
        const float* __restrict__ xx, const float* __restrict__ cent,
        const float* __restrict__ cc, int* __restrict__ asn, int* __restrict__ hist) {
    __shared__ float sc[8192];
    __shared__ float scc[256];
    __shared__ int bins[256];
    int tid = threadIdx.x, c = blockIdx.x;
    {
        const float4* c4 = (const float4*)cent;
        float4* s4 = (float4*)sc;
        for (int i = tid; i < 2048; i += 256) s4[i] = c4[i];
    }
    scc[tid] = cc[tid];
    bins[tid] = 0;
    __syncthreads();
    int pl = tid >> 1, half = tid & 1;
    int p0 = c * 256 + pl * 2, p1 = p0 + 1;
    float x0[32], x1[32];
    {
        const float4* pp0 = (const float4*)(pts + (size_t)p0 * 32);
        const float4* pp1 = (const float4*)(pts + (size_t)p1 * 32);
        #pragma unroll
        for (int t = 0; t < 8; t++) {
            float4 f = pp0[t];
            x0[4*t] = f.x; x0[4*t+1] = f.y; x0[4*t+2] = f.z; x0[4*t+3] = f.w;
            float4 g = pp1[t];
            x1[4*t] = g.x; x1[4*t+1] = g.y; x1[4*t+2] = g.z; x1[4*t+3] = g.w;
        }
    }
    float xp0 = xx[p0], xp1 = xx[p1];
    float bd0 = 3.4e38f, bd1 = 3.4e38f;
    int bj0 = 0, bj1 = 0;
    int jbase = half * 128;
    for (int jj = 0; jj < 128; jj++) {
        int j = jbase + jj;
        const float4* cj = (const float4*)(sc + j * 32);
        float g0 = 0.f, g1 = 0.f;
        #pragma unroll
        for (int t = 0; t < 8; t++) {
            float4 w = cj[t];
            g0 = __builtin_fmaf(x0[4*t],   w.x, g0);
            g0 = __builtin_fmaf(x0[4*t+1], w.y, g0);
            g0 = __builtin_fmaf(x0[4*t+2], w.z, g0);
            g0 = __builtin_fmaf(x0[4*t+3], w.w, g0);
            g1 = __builtin_fmaf(x1[4*t],   w.x, g1);
            g1 = __builtin_fmaf(x1[4*t+1], w.y, g1);
            g1 = __builtin_fmaf(x1[4*t+2], w.z, g1);
            g1 = __builtin_fmaf(x1[4*t+3], w.w, g1);
        }
        float sj = scc[j];
        float d0 = fadd(fsub(xp0, fmul(2.f, g0)), sj);
        float d1 = fadd(fsub(xp1, fmul(2.f, g1)), sj);
        if (d0 < bd0) { bd0 = d0; bj0 = j; }
        if (d1 < bd1) { bd1 = d1; bj1 = j; }
    }
    float obd0 = __shfl_xor(bd0, 1); int obj0 = __shfl_xor(bj0, 1);
    float obd1 = __shfl_xor(bd1, 1); int obj1 = __shfl_xor(bj1, 1);
    if (half == 0) {
        if (obd0 < bd0) { bd0 = obd0; bj0 = obj0; }
        if (obd1 < bd1) { bd1 = obd1; bj1 = obj1; }
        asn[p0] = bj0; asn[p1] = bj1;
        atomicAdd(&bins[bj0], 1);
        atomicAdd(&bins[bj1], 1);
    }
    __syncthreads();
    hist[c * 256 + tid] = bins[tid];
}

// ---------- per-cluster prefix over 256 chunks ----------------------
__global__ __launch_bounds__(256) void scan_chunks(const int* __restrict__ hist,
        int* __restrict__ chunkbase, int* __restrict__ totals) {
    __shared__ int a[256];
    int j = blockIdx.x, c = threadIdx.x;
    a[c] = hist[(size_t)c * 256 + j];
    __syncthreads();
    for (int d = 1; d < 256; d <<= 1) {
        int v = a[c];
        int u = (c >= d) ? a[c - d] : 0;
        __syncthreads();
        a[c] = v + u;
        __syncthreads();
    }
    chunkbase[(size_t)c * 256 + j] = (c == 0) ? 0 : a[c - 1];
    if (c == 255) totals[j] = a[255];
}

// ---------- scatter: parallel cbase scan + stable rank --------------
__global__ __launch_bounds__(256) void scatter_v5(const int* __restrict__ asn,
        const int* __restrict__ chunkbase, const int* __restrict__ totals,
        int* __restrict__ perm) {
    __shared__ int cb[256];
    __shared__ int al[256];
    int c = blockIdx.x, tid = threadIdx.x;
    cb[tid] = totals[tid];
    al[tid] = asn[c * 256 + tid];
    __syncthreads();
    for (int d = 1; d < 256; d <<= 1) {
        int v = cb[tid];
        int u = (tid >= d) ? cb[tid - d] : 0;
        __syncthreads();
        cb[tid] = v + u;
        __syncthreads();
    }
    int my = al[tid];
    int base = (my == 0) ? 0 : cb[my - 1];
    int r = 0;
    for (int i = 0; i < tid; i++) r += (al[i] == my) ? 1 : 0;
    perm[base + chunkbase[(size_t)c * 256 + my] + r] = c * 256 + tid;
}

// ---------- ordered sum + update + cc (parallel cbase scan) ---------
#define STILE 128
__global__ __launch_bounds__(256) void sumk_v4(const float* __restrict__ pts,
        const int* __restrict__ perm, const int* __restrict__ totals,
        float* __restrict__ cent, float* __restrict__ cc) {
    __shared__ int cb[256];
    __shared__ float buf[2][STILE][32];
    int j = blockIdx.x, tid = threadIdx.x;
    cb[tid] = totals[tid];
    __syncthreads();
    for (int d = 1; d < 256; d <<= 1) {
        int v = cb[tid];
        int u = (tid >= d) ? cb[tid - d] : 0;
        __syncthreads();
        cb[tid] = v + u;
        __syncthreads();
    }
    int base = (j == 0) ? 0 : cb[j - 1];
    int n = totals[j];
    int t = tid & 31, r0 = tid >> 5;
    for (int r = r0; r < STILE; r += 8) {
        if (r < n) buf[0][r][t] = pts[(size_t)perm[base + r] * 32 + t];
    }
    __syncthreads();
    float s = 0.f;
    int b = 0;
    for (int i0 = 0; i0 < n; i0 += STILE, b ^= 1) {
        int nx = i0 + STILE;
        if (nx < n) {
            for (int r = r0; r < STILE; r += 8) {
                int g = nx + r;
                if (g < n) buf[b ^ 1][r][t] = pts[(size_t)perm[base + g] * 32 + t];
            }
        }
        if (tid < 32) {
            int m = n - i0; if (m > STILE) m = STILE;
            int i = 0;
            for (; i + 4 <= m; i += 4) {
                s = fadd(s, buf[b][i][tid]);
                s = fadd(s, buf[b][i + 1][tid]);
                s = fadd(s, buf[b][i + 2][tid]);
                s = fadd(s, buf[b][i + 3][tid]);
            }
            for (; i < m; i++) s = fadd(s, buf[b][i][tid]);
        }
        __syncthreads();
    }
    if (tid < 32) {
        float v;
        if (n > 0) {
            v = __fdiv_rn(s, (float)n);
            cent[(size_t)j * 32 + tid] = v;
        } else {
            v = cent[(size_t)j * 32 + tid];
        }
        float e = fmul(v, v);
        e = fadd(e, __shfl_xor(e, 16));
        e = fadd(e, __shfl_xor(e, 8));
        e = fadd(e, __shfl_xor(e, 4));
        e = fadd(e, __shfl_xor(e, 2));
        e = fadd(e, __shfl_xor(e, 1));
        if (tid == 0) cc[j] = e;
    }
}

// ---------- key assign + L1: 2 pts/thread x half clusters -----------
__global__ __launch_bounds__(256) void kdist2_half(const float* __restrict__ pts,
        const float* __restrict__ cent, const float* __restrict__ cc,
        float* __restrict__ kd) {
    __shared__ float sc[8192];
    __shared__ float scc[256];
    int tid = threadIdx.x, c = blockIdx.x;
    {
        const float4* c4 = (const float4*)cent;
        float4* s4 = (float4*)sc;
        for (int i = tid; i < 2048; i += 256) s4[i] = c4[i];
    }
    scc[tid] = cc[tid];
    __syncthreads();
    int pl = tid >> 1, half = tid & 1;
    int p0 = c * 256 + pl * 2, p1 = p0 + 1;
    float x0[32], x1[32];
    {
        const float4* pp0 = (const float4*)(pts + (size_t)p0 * 32);
        const float4* pp1 = (const float4*)(pts + (size_t)p1 * 32);
        #pragma unroll
        for (int t = 0; t < 8; t++) {
            float4 f = pp0[t];
            x0[4*t] = f.x; x0[4*t+1] = f.y; x0[4*t+2] = f.z; x0[4*t+3] = f.w;
            float4 g = pp1[t];
            x1[4*t] = g.x; x1[4*t+1] = g.y; x1[4*t+2] = g.z; x1[4*t+3] = g.w;
        }
    }
    float xp0, xp1;
    {
        float e[32];
        #pragma unroll
        for (int t = 0; t < 32; t++) e[t] = fmul(x0[t], x0[t]);
        xp0 = sum32_np(e);
        #pragma unroll
        for (int t = 0; t < 32; t++) e[t] = fmul(x1[t], x1[t]);
        xp1 = sum32_np(e);
    }
    float bd0 = 3.4e38f, bd1 = 3.4e38f;
    int bj0 = 0, bj1 = 0;
    int jbase = half * 128;
    for (int jj = 0; jj < 128; jj++) {
        int j = jbase + jj;
        const float4* cj = (const float4*)(sc + j * 32);
        float g0 = 0.f, g1 = 0.f;
        #pragma unroll
        for (int t = 0; t < 8; t++) {
            float4 w = cj[t];
            g0 = __builtin_fmaf(x0[4*t],   w.x, g0);
            g0 = __builtin_fmaf(x0[4*t+1], w.y, g0);
            g0 = __builtin_fmaf(x0[4*t+2], w.z, g0);
            g0 = __builtin_fmaf(x0[4*t+3], w.w, g0);
            g1 = __builtin_fmaf(x1[4*t],   w.x, g1);
            g1 = __builtin_fmaf(x1[4*t+1], w.y, g1);
            g1 = __builtin_fmaf(x1[4*t+2], w.z, g1);
            g1 = __builtin_fmaf(x1[4*t+3], w.w, g1);
        }
        float sj = scc[j];
        float d0 = fadd(fsub(xp0, fmul(2.f, g0)), sj);
        float d1 = fadd(fsub(xp1, fmul(2.f, g1)), sj);
        if (d0 < bd0) { bd0 = d0; bj0 = j; }
        if (d1 < bd1) { bd1 = d1; bj1 = j; }
    }
    float obd0 = __shfl_xor(bd0, 1); int obj0 = __shfl_xor(bj0, 1);
    float obd1 = __shfl_xor(bd1, 1); int obj1 = __shfl_xor(bj1, 1);
    if (half == 0) {
        if (obd0 < bd0) { bd0 = obd0; bj0 = obj0; }
        if (obd1 < bd1) { bd1 = obd1; bj1 = obj1; }
        {
            const float* cb = &sc[bj0 * 32];
            float e[32];
            #pragma unroll
            for (int t = 0; t < 32; t++) e[t] = fabsf(fsub(cb[t], x0[t]));
            kd[p0] = sum32_np(e);
        }
        {
            const float* cb = &sc[bj1 * 32];
            float e[32];
            #pragma unroll
            for (int t = 0; t < 32; t++) e[t] = fabsf(fsub(cb[t], x1[t]));
            kd[p1] = sum32_np(e);
        }
    }
}

// ---------- top-256 via radix select (exact stable set) + gather ----
__global__ __launch_bounds__(256) void topk_v2(const float* __restrict__ kd,
        const float* __restrict__ k_t, const float* __restrict__ v_t,
        float* __restrict__ ksel, float* __restrict__ vsel) {
    __shared__ unsigned uv[4096];
    __shared__ int hist[256];
    __shared__ unsigned s_prefix;
    __shared__ int s_rem;
    __shared__ int sc1[256];
    __shared__ int out_src[256];
    int bh = blockIdx.x, tid = threadIdx.x;
    for (int i = tid; i < 4096; i += 256) uv[i] = __float_as_uint(kd[bh * 4096 + i]);
    if (tid == 0) { s_prefix = 0u; s_rem = 256; }
    out_src[tid] = 0;
    __syncthreads();
    for (int pass = 0; pass < 4; pass++) {
        int shift = 24 - 8 * pass;
        hist[tid] = 0;
        __syncthreads();
        unsigned pfx = s_prefix;
        for (int i = tid; i < 4096; i += 256) {
            unsigned u = uv[i];
            bool in = (pass == 0) || ((u >> (shift + 8)) == (pfx >> (shift + 8)));
            if (in) atomicAdd(&hist[(u >> shift) & 255], 1);
        }
        __syncthreads();
        if (tid == 0) {
            int rem = s_rem, cum = 0, b;
            for (b = 255; b >= 0; b--) {
                if (cum + hist[b] >= rem) break;
                cum += hist[b];
            }
            s_rem = rem - cum;
            s_prefix = s_prefix | ((unsigned)b << shift);
        }
        __syncthreads();
    }
    unsigned T = s_prefix;
    int r = s_rem;
    int base_i = tid * 16;
    int ec = 0;
    for (int q = 0; q < 16; q++) ec += (uv[base_i + q] == T) ? 1 : 0;
    sc1[tid] = ec;
    __syncthreads();
    for (int d = 1; d < 256; d <<= 1) {
        int t0 = sc1[tid];
        int u0 = (tid >= d) ? sc1[tid - d] : 0;
        __syncthreads();
        sc1[tid] = t0 + u0;
        __syncthreads();
    }
    int erank = (tid == 0) ? 0 : sc1[tid - 1];
    __syncthreads();
    bool incl[16];
    int ic = 0;
    for (int q = 0; q < 16; q++) {
        unsigned u = uv[base_i + q];
        bool inc;
        if (u > T) inc = true;
        else if (u == T) { inc = (erank < r); erank++; }
        else inc = false;
        incl[q] = inc;
        ic += inc ? 1 : 0;
    }
    sc1[tid] = ic;
    __syncthreads();
    for (int d = 1; d < 256; d <<= 1) {
        int t0 = sc1[tid];
        int u0 = (tid >= d) ? sc1[tid - d] : 0;
        __syncthreads();
        sc1[tid] = t0 + u0;
        __syncthreads();
    }
    int pos = (tid == 0) ? 0 : sc1[tid - 1];
    for (int q = 0; q < 16; q++) {
        if (incl[q]) out_src[pos++] = base_i + q;
    }
    __syncthreads();
    for (int e = tid; e < 256 * 32; e += 256) {
        int jj = e >> 5, t = e & 31;
        int src = out_src[jj];
        ksel[(size_t)bh * 8192 + e] = k_t[((size_t)bh * 4096 + src) * 32 + t];
        vsel[(size_t)bh * 8192 + e] = v_t[((size_t)bh * 4096 + src) * 32 + t];
    }
}

// ---------- attention v3: 2 queries/thread, key-half split ----------
__global__ __launch_bounds__(256) void attn_v3(const float* __restrict__ q_t,
        const float* __restrict__ ksel, const float* __restrict__ vsel,
        float* __restrict__ out) {
    __shared__ float sk[8192];
    __shared__ float sv[8192];
    int bh = blockIdx.y, tid = threadIdx.x;
    {
        const float4* gk = (const float4*)(ksel + (size_t)bh * 8192);
        const float4* gv = (const float4*)(vsel + (size_t)bh * 8192);
        float4* k4s = (float4*)sk; float4* v4s = (float4*)sv;
        for (int i = tid; i < 2048; i += 256) { k4s[i] = gk[i]; v4s[i] = gv[i]; }
    }
    __syncthreads();
    int ql = tid >> 1, slice = tid & 1;
    int p0 = bh * 4096 + blockIdx.x * 256 + ql * 2;
    float q0[32], q1[32];
    {
        const float4* qp0 = (const float4*)(q_t + (size_t)p0 * 32);
        const float4* qp1 = (const float4*)(q_t + (size_t)(p0 + 1) * 32);
        #pragma unroll
        for (int t = 0; t < 8; t++) {
            float4 f = qp0[t];
            q0[4*t] = f.x; q0[4*t+1] = f.y; q0[4*t+2] = f.z; q0[4*t+3] = f.w;
            float4 g = qp1[t];
            q1[4*t] = g.x; q1[4*t+1] = g.y; q1[4*t+2] = g.z; q1[4*t+3] = g.w;
        }
    }
    float o0[32], o1[32];
    #pragma unroll
    for (int t = 0; t < 32; t++) { o0[t] = 0.f; o1[t] = 0.f; }
    float ls0 = 0.f, ls1 = 0.f;
    const float4* k4 = (const float4*)sk;
    const float4* v4 = (const float4*)sv;
    int j0 = slice * 128;
    for (int j = j0; j < j0 + 128; j++) {
        float s0 = 0.f, s1 = 0.f;
        #pragma unroll
        for (int t = 0; t < 8; t++) {
            float4 kf = k4[j * 8 + t];
            s0 += q0[4*t]*kf.x + q0[4*t+1]*kf.y + q0[4*t+2]*kf.z + q0[4*t+3]*kf.w;
            s1 += q1[4*t]*kf.x + q1[4*t+1]*kf.y + q1[4*t+2]*kf.z + q1[4*t+3]*kf.w;
        }
        float w0 = __expf(s0 - 1.0f);   // s <= 1 (unit vectors)
        float w1 = __expf(s1 - 1.0f);
        ls0 += w0; ls1 += w1;
        #pragma unroll
        for (int t = 0; t < 8; t++) {
            float4 vf = v4[j * 8 + t];
            o0[4*t]   += w0 * vf.x; o0[4*t+1] += w0 * vf.y;
            o0[4*t+2] += w0 * vf.z; o0[4*t+3] += w0 * vf.w;
            o1[4*t]   += w1 * vf.x; o1[4*t+1] += w1 * vf.y;
            o1[4*t+2] += w1 * vf.z; o1[4*t+3] += w1 * vf.w;
        }
    }
    #pragma unroll
    for (int t = 0; t < 32; t++) {
        o0[t] += __shfl_xor(o0[t], 1);
        o1[t] += __shfl_xor(o1[t], 1);
    }
    ls0 += __shfl_xor(ls0, 1);
    ls1 += __shfl_xor(ls1, 1);
    if (slice == 0) {
        float inv0 = 1.f / ls0, inv1 = 1.f / ls1;
        float4* op0 = (float4*)(out + (size_t)p0 * 32);
        float4* op1 = (float4*)(out + (size_t)(p0 + 1) * 32);
        #pragma unroll
        for (int t = 0; t < 8; t++) {
            op0[t] = make_float4(o0[4*t]*inv0, o0[4*t+1]*inv0, o0[4*t+2]*inv0, o0[4*t+3]*inv0);
            op1[t] = make_float4(o1[4*t]*inv1, o1[4*t+1]*inv1, o1[4*t+2]*inv1, o1[4*t+3]*inv1);
        }
    }
}

// ---------- unfold (bh,L,32) -> (b,256,L) ---------------------------
__global__ __launch_bounds__(256) void unfold_kernel(const float* __restrict__ att,
        float* __restrict__ Fo) {
    __shared__ float tbuf[32][65];
    int bh = blockIdx.y, l0 = blockIdx.x * 64;
    int b = bh >> 3, h = bh & 7;
    int tid = threadIdx.x;
    #pragma unroll
    for (int r = 0; r < 8; r++) {
        int e = r * 256 + tid;
        int l = e >> 5, d = e & 31;
        tbuf[d][l] = att[((size_t)bh * 4096 + l0 + l) * 32 + d];
    }
    __syncthreads();
    #pragma unroll
    for (int r = 0; r < 8; r++) {
        int e = r * 256 + tid;
        int d = e >> 6, l = e & 63;
        Fo[((size_t)b * 256 + h * 32 + d) * LSEQ + l0 + l] = tbuf[d][l];
    }
}

// ---------- final LN + scale + residual (numpy orders) --------------
__global__ __launch_bounds__(64) void lnres_np(const float* __restrict__ x,
        const float* __restrict__ g, const float* __restrict__ bt,
        const float* __restrict__ gs, const float* __restrict__ qsrc,
        float* __restrict__ y) {
    int gid = blockIdx.x * 64 + threadIdx.x;
    int b = gid >> 12, l = gid & 4095;
    const float* xb = x + (size_t)b * CDIM * LSEQ + l;
    float s = 0.f;
    for (int c = 0; c < 256; c++) s = fadd(s, xb[(size_t)c * LSEQ]);
    float mean = __fdiv_rn(s, 256.f);
    float s2 = 0.f;
    for (int c = 0; c < 256; c++) {
        float d = fsub(xb[(size_t)c * LSEQ], mean);
        s2 = fadd(s2, fmul(d, d));
    }
    float var = __fdiv_rn(s2, 256.f);
    float den = fadd(__fsqrt_rn(var), 1e-6f);
    float scale = gs[0];
    const float* qb = qsrc + (size_t)b * CDIM * LSEQ + l;
    float* yb = y + (size_t)b * CDIM * LSEQ + l;
    for (int c = 0; c < 256; c++) {
        float d = fsub(xb[(size_t)c * LSEQ], mean);
        float r = fadd(__fdiv_rn(fmul(g[c], d), den), bt[c]);
        yb[(size_t)c * LSEQ] = fadd(fmul(scale, r), qb[(size_t)c * LSEQ]);
    }
}

// ==================================================================
extern "C" void kernel_launch(void* const* d_in, const int* in_sizes, int n_in,
                              void* d_out, int out_size, void* d_ws, size_t ws_size,
                              hipStream_t stream) {
    const float* qsrc   = (const float*)d_in[0];
    const float* ctx    = (const float*)d_in[1];
    const float* w_q    = (const float*)d_in[2];
    const float* w_kv   = (const float*)d_in[3];
    const float* w_out  = (const float*)d_in[4];
    const float* g_ctx  = (const float*)d_in[5];
    const float* b_ctx  = (const float*)d_in[6];
    const float* g_q    = (const float*)d_in[7];
    const float* b_q    = (const float*)d_in[8];
    const float* g_out  = (const float*)d_in[9];
    const float* b_out  = (const float*)d_in[10];
    const float* gs     = (const float*)d_in[11];

    char* base = (char*)d_ws;
    const size_t MB = 1024 * 1024;
    float* yln   = (float*)base;               // [0,8) LN out; later att
    float* att   = (float*)base;
    float* kvbuf = (float*)(base + 8 * MB);    // [8,24) kv conv; later y32 [8,16)
    float* y32   = (float*)(base + 8 * MB);
    float* qbuf  = (float*)(base + 24 * MB);   // [24,32) q conv; later Fo
    float* Fo    = (float*)(base + 24 * MB);
    float* q_t   = (float*)(base + 32 * MB);   // [32,40)
    float* k_t   = (float*)(base + 40 * MB);   // [40,48)
    float* v_t   = (float*)(base + 48 * MB);   // [48,56)
    char* SM = base + 56 * MB;
    float* xx_q      = (float*)(SM + 0);            // 256 KB
    float* cent      = (float*)(SM + 512 * 1024);   // 32 KB
    float* cc        = (float*)(SM + 576 * 1024);   // 1 KB
    int*   totals    = (int*)  (SM + 640 * 1024);   // 1 KB
    int*   asn       = (int*)  (SM + 704 * 1024);   // 256 KB
    int*   hist      = (int*)  (SM + 960 * 1024);   // 256 KB
    int*   chunkbase = (int*)  (SM + 1472 * 1024);  // 256 KB
    int*   perm      = (int*)  (SM + 1984 * 1024);  // 256 KB
    float* kd        = (float*)(SM + 2240 * 1024);  // 256 KB
    float* ksel      = (float*)(SM + 2496 * 1024);  // 512 KB
    float* vsel      = (float*)(SM + 3008 * 1024);  // 512 KB

    // context branch
    ln_np<<<128, 64, 0, stream>>>(ctx, g_ctx, b_ctx, yln);
    conv_nl<16, 2><<<dim3(8, 32, 2), 256, 0, stream>>>(w_kv, 0, yln, kvbuf, 512);
    fold_np<<<256, 256, 0, stream>>>(kvbuf, 512, 0, 1, k_t);
    fold_np<<<256, 256, 0, stream>>>(kvbuf, 512, 256, 0, v_t);
    // query branch
    ln_np<<<128, 64, 0, stream>>>(qsrc, g_q, b_q, yln);
    conv_nl<8, 2><<<dim3(8, 32, 2), 256, 0, stream>>>(w_q, 0, yln, qbuf, 256);
    fold_np<<<256, 256, 0, stream>>>(qbuf, 256, 0, 1, q_t);

    xx_np<<<256, 256, 0, stream>>>(q_t, xx_q);
    copy32<<<32, 256, 0, stream>>>(q_t, cent, 8192);
    cc_np<<<1, 256, 0, stream>>>(cent, cc);

    for (int it = 0; it < 10; it++) {
        assign2_half<<<256, 256, 0, stream>>>(q_t, xx_q, cent, cc, asn, hist);
        scan_chunks<<<256, 256, 0, stream>>>(hist, chunkbase, totals);
        scatter_v5<<<256, 256, 0, stream>>>(asn, chunkbase, totals, perm);
        sumk_v4<<<256, 256, 0, stream>>>(q_t, perm, totals, cent, cc);
    }

    kdist2_half<<<256, 256, 0, stream>>>(k_t, cent, cc, kd);
    topk_v2<<<16, 256, 0, stream>>>(kd, k_t, v_t, ksel, vsel);
    attn_v3<<<dim3(16, 16), 256, 0, stream>>>(q_t, ksel, vsel, att);
    unfold_kernel<<<dim3(64, 16), 256, 0, stream>>>(att, Fo);
    conv_nl<8, 2><<<dim3(8, 32, 2), 256, 0, stream>>>(w_out, 0, Fo, y32, 256);
    lnres_np<<<128, 64, 0, stream>>>(y32, g_out, b_out, gs, qsrc, (float*)d_out);
}